// Round 1
// baseline (1550.105 us; speedup 1.0000x reference)
//
#include <hip/hip_runtime.h>
#include <stdint.h>

typedef unsigned int u32;
typedef unsigned char u8;

#define N_NODES 500000
#define N_EDGES 16000000
#define MASK_DEPTH 3
#define BLK 256
#define EDGE_GRID 2048
#define NODE_GRID 1024
#define TIE_CAP 8192

// JAX PRNG mode: 1 = partitionable (default for JAX >= 0.4.30), 0 = original threefry layout.
// If bench fails with masked-output absmax ~1.0, flip this to 0.
#define TF_PARTITIONABLE 1

// ---------------- workspace layout (bytes) ----------------
#define OFF_MBITS   0u         // u32[N_EDGES/32]  = 2,000,000 B
#define OFF_ISSEED  2000000u   // u8[N_NODES]      =   500,000 B
#define OFF_CAND    2500000u   // u8[N_NODES]      =   500,000 B
#define OFF_MVALS   3000000u   // u32[N_NODES]     = 2,000,000 B
#define OFF_DEG     5000000u   // f32[N_NODES]     = 2,000,000 B
#define OFF_HIST1   7000000u   // u32[4096]
#define OFF_HIST2   7016384u   // u32[2048]
#define OFF_TIEBUF  7024576u   // u32[TIE_CAP]
#define OFF_SCAL    7057344u   // u32[64]
#define WS_NEED     7057600u
// scalars: [0]=n_cand [1]=keep_num [2]=b* [3]=rem1 [4]=m* [5]=rem2 [6]=tie_count [7]=any_alive [8]=valid

// Threefry-2x32, 20 rounds (exactly JAX's threefry2x32_p)
__host__ __device__ inline void tf2x32(u32 k0, u32 k1, u32 x0, u32 x1, u32& o0, u32& o1) {
  u32 ks0 = k0, ks1 = k1, ks2 = k0 ^ k1 ^ 0x1BD11BDAu;
  x0 += ks0; x1 += ks1;
#define TFR(r) { x0 += x1; x1 = (x1 << (r)) | (x1 >> (32 - (r))); x1 ^= x0; }
  TFR(13) TFR(15) TFR(26) TFR(6)   x0 += ks1; x1 += ks2 + 1u;
  TFR(17) TFR(29) TFR(16) TFR(24)  x0 += ks2; x1 += ks0 + 2u;
  TFR(13) TFR(15) TFR(26) TFR(6)   x0 += ks0; x1 += ks1 + 3u;
  TFR(17) TFR(29) TFR(16) TFR(24)  x0 += ks1; x1 += ks2 + 4u;
  TFR(13) TFR(15) TFR(26) TFR(6)   x0 += ks2; x1 += ks0 + 5u;
#undef TFR
  o0 = x0; o1 = x1;
}

__global__ void k_scatter_seeds(const int* __restrict__ seeds, int ns, u8* __restrict__ is_seed) {
  int i = blockIdx.x * blockDim.x + threadIdx.x;
  if (i < ns) is_seed[seeds[i]] = 1;
}

// Mark edges touching seeds; fused candidate marking (endpoints of newly masked edges).
__global__ void k_mark(const int* __restrict__ rows, const int* __restrict__ cols,
                       u32* __restrict__ mbits, const u8* __restrict__ is_seed,
                       u8* __restrict__ cand, int do_cand) {
  int stride = gridDim.x * blockDim.x;
  for (int e = blockIdx.x * blockDim.x + threadIdx.x; e < N_EDGES; e += stride) {
    u32 w = mbits[e >> 5];
    if (w & (1u << (e & 31))) continue;       // already masked (own bit only set by own thread in prior depths)
    int r = rows[e], c = cols[e];
    if (is_seed[r] | is_seed[c]) {
      atomicOr(&mbits[e >> 5], 1u << (e & 31));
      if (do_cand) { cand[r] = 1; cand[c] = 1; }
    }
  }
}

__global__ void k_count_cand(const u8* __restrict__ cand, u32* __restrict__ scalars) {
  __shared__ u32 red[BLK];
  u32 s = 0;
  int stride = gridDim.x * blockDim.x;
  for (int v = blockIdx.x * blockDim.x + threadIdx.x; v < N_NODES; v += stride) s += cand[v];
  red[threadIdx.x] = s; __syncthreads();
  for (int o = BLK / 2; o > 0; o >>= 1) {
    if (threadIdx.x < (u32)o) red[threadIdx.x] += red[threadIdx.x + o];
    __syncthreads();
  }
  if (threadIdx.x == 0) atomicAdd(&scalars[0], red[0]);
}

// Per-node uniform bits (only top 23 bits matter for ranking) + coarse histogram over candidates.
__global__ void k_mvals_hist1(u32 s0, u32 s1, const u8* __restrict__ cand,
                              u32* __restrict__ mvals, u32* __restrict__ hist1) {
#if TF_PARTITIONABLE
  int stride = gridDim.x * blockDim.x;
  for (int v = blockIdx.x * blockDim.x + threadIdx.x; v < N_NODES; v += stride) {
    u32 a, b; tf2x32(s0, s1, 0u, (u32)v, a, b);
    u32 m = (a ^ b) >> 9;
    mvals[v] = m;
    if (cand[v]) atomicAdd(&hist1[m >> 11], 1u);
  }
#else
  const int H = N_NODES / 2;
  int stride = gridDim.x * blockDim.x;
  for (int j = blockIdx.x * blockDim.x + threadIdx.x; j < H; j += stride) {
    u32 a, b; tf2x32(s0, s1, (u32)j, (u32)(j + H), a, b);
    u32 m0 = a >> 9, m1 = b >> 9;
    mvals[j] = m0; mvals[j + H] = m1;
    if (cand[j])     atomicAdd(&hist1[m0 >> 11], 1u);
    if (cand[j + H]) atomicAdd(&hist1[m1 >> 11], 1u);
  }
#endif
}

// Single block (256 threads): find bucket containing the K-th smallest; write bucket + remainder.
template <int NB>
__global__ void k_find_bucket(const u32* __restrict__ hist, u32* __restrict__ scalars,
                              int stage, int shift) {
  __shared__ u32 warpsum[BLK / 64];
  int tid = threadIdx.x;
  u32 K, valid;
  if (stage == 0) {
    u32 nc = scalars[0];
    K = nc >> shift;                       // == floor(n_cand * 0.5^(i+1)) exactly
    valid = (K > 0) ? 1u : 0u;
    if (tid == 0) { scalars[1] = K; scalars[8] = valid; }
  } else {
    valid = scalars[8];
    K = scalars[3];
  }
  if (!valid) return;
  constexpr int CH = NB / BLK;
  u32 loc[CH];
  u32 s = 0;
  int base = tid * CH;
#pragma unroll
  for (int i = 0; i < CH; i++) { loc[i] = hist[base + i]; s += loc[i]; }
  // wave-inclusive scan of per-thread sums
  u32 x = s;
  for (int off = 1; off < 64; off <<= 1) {
    u32 y = __shfl_up(x, off, 64);
    if ((tid & 63) >= off) x += y;
  }
  if ((tid & 63) == 63) warpsum[tid >> 6] = x;
  __syncthreads();
  u32 woff = 0;
  for (int w = 0; w < (tid >> 6); w++) woff += warpsum[w];
  u32 run = woff + x - s;                  // exclusive prefix of this thread's chunk
#pragma unroll
  for (int i = 0; i < CH; i++) {
    u32 h = loc[i];
    if (h && K > run && K <= run + h) {    // unique crossing bucket
      if (stage == 0) { scalars[2] = (u32)(base + i); scalars[3] = K - run; }
      else            { scalars[4] = (scalars[2] << 11) | (u32)(base + i); scalars[5] = K - run; }
    }
    run += h;
  }
}

__global__ void k_hist2(const u8* __restrict__ cand, const u32* __restrict__ mvals,
                        const u32* __restrict__ scalars, u32* __restrict__ hist2) {
  if (!scalars[8]) return;
  u32 bstar = scalars[2];
  int stride = gridDim.x * blockDim.x;
  for (int v = blockIdx.x * blockDim.x + threadIdx.x; v < N_NODES; v += stride) {
    if (cand[v]) {
      u32 m = mvals[v];
      if ((m >> 11) == bstar) atomicAdd(&hist2[m & 2047u], 1u);
    }
  }
}

// is_seed[v] = cand && m < m*; ties (m == m*) appended for index-ordered tie-break.
__global__ void k_select(const u8* __restrict__ cand, const u32* __restrict__ mvals,
                         u32* __restrict__ scalars, u8* __restrict__ is_seed,
                         u32* __restrict__ tiebuf) {
  u32 valid = scalars[8];
  u32 mstar = scalars[4];
  int stride = gridDim.x * blockDim.x;
  for (int v = blockIdx.x * blockDim.x + threadIdx.x; v < N_NODES; v += stride) {
    u8 s = 0;
    if (valid && cand[v]) {
      u32 m = mvals[v];
      if (m < mstar) s = 1;
      else if (m == mstar) {
        u32 p = atomicAdd(&scalars[6], 1u);
        if (p < TIE_CAP) tiebuf[p] = (u32)v;
      }
    }
    is_seed[v] = s;   // full replacement, matches reference semantics
  }
}

// Stable tie-break: among nodes with m == m*, keep the rem2 smallest node indices.
__global__ void k_ties(u32* __restrict__ scalars, const u32* __restrict__ tiebuf,
                       u8* __restrict__ is_seed) {
  if (!scalars[8]) return;
  u32 T = scalars[6]; if (T > TIE_CAP) T = TIE_CAP;
  u32 rem2 = scalars[5];
  for (u32 i = threadIdx.x; i < T; i += blockDim.x) {
    u32 v = tiebuf[i];
    u32 rank = 0;
    for (u32 j = 0; j < T; j++) rank += (tiebuf[j] < v) ? 1u : 0u;
    if (rank < rem2) is_seed[v] = 1;
  }
}

__global__ void k_deg(const int* __restrict__ rows, const u32* __restrict__ mbits,
                      float* __restrict__ deg, u32* __restrict__ scalars) {
  __shared__ int anyb;
  if (threadIdx.x == 0) anyb = 0;
  __syncthreads();
  int any = 0;
  int stride = gridDim.x * blockDim.x;
  for (int e = blockIdx.x * blockDim.x + threadIdx.x; e < N_EDGES; e += stride) {
    if (!((mbits[e >> 5] >> (e & 31)) & 1u)) { atomicAdd(&deg[rows[e]], 1.0f); any = 1; }
  }
  if (any) anyb = 1;
  __syncthreads();
  if (threadIdx.x == 0 && anyb) scalars[7] = 1u;
}

__global__ void k_dinv(float* __restrict__ deg) {
  int v = blockIdx.x * blockDim.x + threadIdx.x;
  if (v < N_NODES) deg[v] = 1.0f / sqrtf(deg[v] + 1e-12f);
}

__global__ void k_final(const int* __restrict__ rows, const int* __restrict__ cols,
                        const float* __restrict__ vals, const u32* __restrict__ mbits,
                        const float* __restrict__ dinv, const u32* __restrict__ scalars,
                        float* __restrict__ out) {
  u32 anyAlive = scalars[7];
  int stride = gridDim.x * blockDim.x;
  for (int e = blockIdx.x * blockDim.x + threadIdx.x; e < N_EDGES; e += stride) {
    u32 mb = (mbits[e >> 5] >> (e & 31)) & 1u;
    float nv = 0.0f;
    if (!mb) nv = dinv[rows[e]] * dinv[cols[e]];
    float enc;
    if (anyAlive) enc = nv;       // uniform branch; vals never loaded in the hot case
    else          enc = vals[e];
    out[e] = enc;
    out[N_EDGES + e] = mb ? 1.0f : 0.0f;
  }
}

extern "C" void kernel_launch(void* const* d_in, const int* in_sizes, int n_in,
                              void* d_out, int out_size, void* d_ws, size_t ws_size,
                              hipStream_t stream) {
  const int*   rows  = (const int*)d_in[0];
  const int*   cols  = (const int*)d_in[1];
  const float* vals  = (const float*)d_in[2];
  const int*   seeds = (const int*)d_in[3];
  int n_seeds = in_sizes[3];
  float* out = (float*)d_out;

  if (ws_size < WS_NEED) return;   // clean failure instead of corruption

  char* ws = (char*)d_ws;
  u32*   mbits  = (u32*)(ws + OFF_MBITS);
  u8*    iseed  = (u8*)(ws + OFF_ISSEED);
  u8*    cand   = (u8*)(ws + OFF_CAND);
  u32*   mvals  = (u32*)(ws + OFF_MVALS);
  float* deg    = (float*)(ws + OFF_DEG);
  u32*   hist1  = (u32*)(ws + OFF_HIST1);
  u32*   hist2  = (u32*)(ws + OFF_HIST2);
  u32*   tiebuf = (u32*)(ws + OFF_TIEBUF);
  u32*   scal   = (u32*)(ws + OFF_SCAL);

  // ----- host-side key derivation: key = jax.random.key(42) = (0, 42); two splits -----
  u32 sub[2][2];
  u32 ka = 0u, kb = 42u;
  for (int i = 0; i < 2; i++) {
#if TF_PARTITIONABLE
    u32 nk0, nk1, sa, sb;
    tf2x32(ka, kb, 0u, 0u, nk0, nk1);   // keys[0] -> new key
    tf2x32(ka, kb, 0u, 1u, sa, sb);     // keys[1] -> sub
    sub[i][0] = sa; sub[i][1] = sb;
    ka = nk0; kb = nk1;
#else
    u32 a0, a1, b0, b1;
    tf2x32(ka, kb, 0u, 2u, a0, a1);     // pair (0,2)
    tf2x32(ka, kb, 1u, 3u, b0, b1);     // pair (1,3)
    sub[i][0] = a1; sub[i][1] = b1;     // sub = (o1(0,2), o1(1,3))
    ka = a0; kb = b0;                   // key = (o0(0,2), o0(1,3))
#endif
  }

  hipMemsetAsync(ws, 0, WS_NEED, stream);
  k_scatter_seeds<<<(n_seeds + BLK - 1) / BLK, BLK, 0, stream>>>(seeds, n_seeds, iseed);

  for (int i = 0; i < MASK_DEPTH; i++) {
    if (i > 0) {
      hipMemsetAsync(cand, 0, N_NODES, stream);
      hipMemsetAsync(ws + OFF_HIST1, 0, WS_NEED - OFF_HIST1, stream);
    }
    int do_cand = (i != MASK_DEPTH - 1);
    k_mark<<<EDGE_GRID, BLK, 0, stream>>>(rows, cols, mbits, iseed, cand, do_cand);
    if (!do_cand) break;
    k_count_cand<<<NODE_GRID, BLK, 0, stream>>>(cand, scal);
    k_mvals_hist1<<<NODE_GRID, BLK, 0, stream>>>(sub[i][0], sub[i][1], cand, mvals, hist1);
    k_find_bucket<4096><<<1, BLK, 0, stream>>>(hist1, scal, 0, i + 1);
    k_hist2<<<NODE_GRID, BLK, 0, stream>>>(cand, mvals, scal, hist2);
    k_find_bucket<2048><<<1, BLK, 0, stream>>>(hist2, scal, 1, 0);
    k_select<<<NODE_GRID, BLK, 0, stream>>>(cand, mvals, scal, iseed, tiebuf);
    k_ties<<<1, BLK, 0, stream>>>(scal, tiebuf, iseed);
  }

  k_deg<<<EDGE_GRID, BLK, 0, stream>>>(rows, mbits, deg, scal);
  k_dinv<<<(N_NODES + BLK - 1) / BLK, BLK, 0, stream>>>(deg);
  k_final<<<EDGE_GRID, BLK, 0, stream>>>(rows, cols, vals, mbits, deg, scal, out);
}

// Round 2
// 1060.517 us; speedup vs baseline: 1.4617x; 1.4617x over previous
//
#include <hip/hip_runtime.h>
#include <stdint.h>

typedef unsigned int u32;
typedef unsigned char u8;

#define N_NODES 500000
#define N_EDGES 16000000
#define MASK_DEPTH 3
#define BLK 256
#define EDGE_GRID 2048
#define NODE_GRID 1024
#define TIE_CAP 8192
#define SEED_WORDS 15625           // ceil(500000/32)
#define MARK_BLK 512
#define MARK_GRID 512              // 2 blocks/CU x 256 CUs

#define TF_PARTITIONABLE 1

// ---------------- workspace layout (bytes) ----------------
#define OFF_MBITS   0u             // u32[N_EDGES/32]   = 2,000,000 B
#define OFF_SEEDB   2000000u       // u32[SEED_WORDS]   =    62,500 B (+pad)
#define OFF_CAND    2062528u       // u8[N_NODES]       =   500,000 B
#define OFF_MVALS   2562528u       // u32[N_NODES]      = 2,000,000 B
#define OFF_DEG     4562528u       // f32[N_NODES]      = 2,000,000 B
#define OFF_HIST1   6562528u       // u32[4096]
#define OFF_HIST2   6578912u       // u32[2048]
#define OFF_TIEBUF  6587104u       // u32[TIE_CAP]
#define OFF_SCAL    6619872u       // u32[64]
#define WS_NEED     6620128u
// scalars: [0]=n_cand [1]=keep_num [2]=b* [3]=rem1 [4]=m* [5]=rem2 [6]=tie_count [7]=any_alive [8]=valid

// Threefry-2x32, 20 rounds (exactly JAX's threefry2x32_p)
__host__ __device__ inline void tf2x32(u32 k0, u32 k1, u32 x0, u32 x1, u32& o0, u32& o1) {
  u32 ks0 = k0, ks1 = k1, ks2 = k0 ^ k1 ^ 0x1BD11BDAu;
  x0 += ks0; x1 += ks1;
#define TFR(r) { x0 += x1; x1 = (x1 << (r)) | (x1 >> (32 - (r))); x1 ^= x0; }
  TFR(13) TFR(15) TFR(26) TFR(6)   x0 += ks1; x1 += ks2 + 1u;
  TFR(17) TFR(29) TFR(16) TFR(24)  x0 += ks2; x1 += ks0 + 2u;
  TFR(13) TFR(15) TFR(26) TFR(6)   x0 += ks0; x1 += ks1 + 3u;
  TFR(17) TFR(29) TFR(16) TFR(24)  x0 += ks1; x1 += ks2 + 4u;
  TFR(13) TFR(15) TFR(26) TFR(6)   x0 += ks2; x1 += ks0 + 5u;
#undef TFR
  o0 = x0; o1 = x1;
}

__global__ void k_scatter_seeds(const int* __restrict__ seeds, int ns, u32* __restrict__ seedbits) {
  int i = blockIdx.x * blockDim.x + threadIdx.x;
  if (i < ns) {
    int v = seeds[i];
    atomicOr(&seedbits[v >> 5], 1u << (v & 31));
  }
}

// Edges touching seeds -> mask bit; endpoints of newly masked edges -> cand.
// Seed membership staged as a 62.5KB bitset in LDS (2 blocks/CU).
__global__ __launch_bounds__(MARK_BLK) void
k_mark(const int* __restrict__ rows, const int* __restrict__ cols,
       u32* __restrict__ mbits, const u32* __restrict__ seedbits,
       u8* __restrict__ cand, int do_cand) {
  __shared__ u32 sb[SEED_WORDS];
  for (int w = threadIdx.x; w < SEED_WORDS; w += MARK_BLK) sb[w] = seedbits[w];
  __syncthreads();
  int stride = gridDim.x * blockDim.x * 4;
  for (int e0 = (blockIdx.x * blockDim.x + threadIdx.x) * 4; e0 < N_EDGES; e0 += stride) {
    u32 mw = mbits[e0 >> 5];
    u32 q  = (mw >> (e0 & 31)) & 0xFu;           // masked-bits of this quad
    if (q == 0xFu) continue;                     // whole quad already masked
    int4 r4 = *reinterpret_cast<const int4*>(rows + e0);
    int4 c4 = *reinterpret_cast<const int4*>(cols + e0);
    u32 newm = 0;
    const int rr[4] = {r4.x, r4.y, r4.z, r4.w};
    const int cc[4] = {c4.x, c4.y, c4.z, c4.w};
#pragma unroll
    for (int j = 0; j < 4; j++) {
      if ((q >> j) & 1u) continue;
      int r = rr[j], c = cc[j];
      u32 hr = (sb[r >> 5] >> (r & 31)) & 1u;
      u32 hc = (sb[c >> 5] >> (c & 31)) & 1u;
      if (hr | hc) {
        newm |= 1u << ((e0 & 31) + j);
        if (do_cand) { cand[r] = 1; cand[c] = 1; }
      }
    }
    if (newm) atomicOr(&mbits[e0 >> 5], newm);
  }
}

__global__ void k_count_cand(const u8* __restrict__ cand, u32* __restrict__ scalars) {
  __shared__ u32 red[BLK];
  u32 s = 0;
  int stride = gridDim.x * blockDim.x;
  for (int v = blockIdx.x * blockDim.x + threadIdx.x; v < N_NODES; v += stride) s += cand[v];
  red[threadIdx.x] = s; __syncthreads();
  for (int o = BLK / 2; o > 0; o >>= 1) {
    if (threadIdx.x < (u32)o) red[threadIdx.x] += red[threadIdx.x + o];
    __syncthreads();
  }
  if (threadIdx.x == 0) atomicAdd(&scalars[0], red[0]);
}

// Per-node uniform bits (top 23 bits rank-determining) + coarse histogram over candidates.
__global__ void k_mvals_hist1(u32 s0, u32 s1, const u8* __restrict__ cand,
                              u32* __restrict__ mvals, u32* __restrict__ hist1) {
#if TF_PARTITIONABLE
  int stride = gridDim.x * blockDim.x;
  for (int v = blockIdx.x * blockDim.x + threadIdx.x; v < N_NODES; v += stride) {
    u32 a, b; tf2x32(s0, s1, 0u, (u32)v, a, b);
    u32 m = (a ^ b) >> 9;
    mvals[v] = m;
    if (cand[v]) atomicAdd(&hist1[m >> 11], 1u);
  }
#else
  const int H = N_NODES / 2;
  int stride = gridDim.x * blockDim.x;
  for (int j = blockIdx.x * blockDim.x + threadIdx.x; j < H; j += stride) {
    u32 a, b; tf2x32(s0, s1, (u32)j, (u32)(j + H), a, b);
    u32 m0 = a >> 9, m1 = b >> 9;
    mvals[j] = m0; mvals[j + H] = m1;
    if (cand[j])     atomicAdd(&hist1[m0 >> 11], 1u);
    if (cand[j + H]) atomicAdd(&hist1[m1 >> 11], 1u);
  }
#endif
}

// Single block: find bucket containing the K-th smallest; write bucket + remainder.
template <int NB>
__global__ void k_find_bucket(const u32* __restrict__ hist, u32* __restrict__ scalars,
                              int stage, int shift) {
  __shared__ u32 warpsum[BLK / 64];
  int tid = threadIdx.x;
  u32 K, valid;
  if (stage == 0) {
    u32 nc = scalars[0];
    K = nc >> shift;                       // == floor(n_cand * 0.5^(i+1)) exactly
    valid = (K > 0) ? 1u : 0u;
    if (tid == 0) { scalars[1] = K; scalars[8] = valid; }
  } else {
    valid = scalars[8];
    K = scalars[3];
  }
  if (!valid) return;
  constexpr int CH = NB / BLK;
  u32 loc[CH];
  u32 s = 0;
  int base = tid * CH;
#pragma unroll
  for (int i = 0; i < CH; i++) { loc[i] = hist[base + i]; s += loc[i]; }
  u32 x = s;
  for (int off = 1; off < 64; off <<= 1) {
    u32 y = __shfl_up(x, off, 64);
    if ((tid & 63) >= off) x += y;
  }
  if ((tid & 63) == 63) warpsum[tid >> 6] = x;
  __syncthreads();
  u32 woff = 0;
  for (int w = 0; w < (tid >> 6); w++) woff += warpsum[w];
  u32 run = woff + x - s;
#pragma unroll
  for (int i = 0; i < CH; i++) {
    u32 h = loc[i];
    if (h && K > run && K <= run + h) {
      if (stage == 0) { scalars[2] = (u32)(base + i); scalars[3] = K - run; }
      else            { scalars[4] = (scalars[2] << 11) | (u32)(base + i); scalars[5] = K - run; }
    }
    run += h;
  }
}

__global__ void k_hist2(const u8* __restrict__ cand, const u32* __restrict__ mvals,
                        const u32* __restrict__ scalars, u32* __restrict__ hist2) {
  if (!scalars[8]) return;
  u32 bstar = scalars[2];
  int stride = gridDim.x * blockDim.x;
  for (int v = blockIdx.x * blockDim.x + threadIdx.x; v < N_NODES; v += stride) {
    if (cand[v]) {
      u32 m = mvals[v];
      if ((m >> 11) == bstar) atomicAdd(&hist2[m & 2047u], 1u);
    }
  }
}

// seedbits must be zeroed before this (full-replacement semantics).
__global__ void k_select(const u8* __restrict__ cand, const u32* __restrict__ mvals,
                         u32* __restrict__ scalars, u32* __restrict__ seedbits,
                         u32* __restrict__ tiebuf) {
  if (!scalars[8]) return;
  u32 mstar = scalars[4];
  int stride = gridDim.x * blockDim.x;
  for (int v = blockIdx.x * blockDim.x + threadIdx.x; v < N_NODES; v += stride) {
    if (cand[v]) {
      u32 m = mvals[v];
      if (m < mstar) atomicOr(&seedbits[v >> 5], 1u << (v & 31));
      else if (m == mstar) {
        u32 p = atomicAdd(&scalars[6], 1u);
        if (p < TIE_CAP) tiebuf[p] = (u32)v;
      }
    }
  }
}

// Stable tie-break: among nodes with m == m*, keep the rem2 smallest node indices.
__global__ void k_ties(u32* __restrict__ scalars, const u32* __restrict__ tiebuf,
                       u32* __restrict__ seedbits) {
  if (!scalars[8]) return;
  u32 T = scalars[6]; if (T > TIE_CAP) T = TIE_CAP;
  u32 rem2 = scalars[5];
  for (u32 i = threadIdx.x; i < T; i += blockDim.x) {
    u32 v = tiebuf[i];
    u32 rank = 0;
    for (u32 j = 0; j < T; j++) rank += (tiebuf[j] < v) ? 1u : 0u;
    if (rank < rem2) atomicOr(&seedbits[v >> 5], 1u << (v & 31));
  }
}

__global__ void k_deg(const int* __restrict__ rows, const u32* __restrict__ mbits,
                      float* __restrict__ deg, u32* __restrict__ scalars) {
  __shared__ int anyb;
  if (threadIdx.x == 0) anyb = 0;
  __syncthreads();
  int any = 0;
  int stride = gridDim.x * blockDim.x * 4;
  for (int e0 = (blockIdx.x * blockDim.x + threadIdx.x) * 4; e0 < N_EDGES; e0 += stride) {
    u32 q = (mbits[e0 >> 5] >> (e0 & 31)) & 0xFu;
    if (q == 0xFu) continue;
    int4 r4 = *reinterpret_cast<const int4*>(rows + e0);
    const int rr[4] = {r4.x, r4.y, r4.z, r4.w};
#pragma unroll
    for (int j = 0; j < 4; j++) {
      if (!((q >> j) & 1u)) { atomicAdd(&deg[rr[j]], 1.0f); any = 1; }
    }
  }
  if (any) anyb = 1;
  __syncthreads();
  if (threadIdx.x == 0 && anyb) scalars[7] = 1u;
}

__global__ void k_dinv(float* __restrict__ deg) {
  int v = blockIdx.x * blockDim.x + threadIdx.x;
  if (v < N_NODES) deg[v] = 1.0f / sqrtf(deg[v] + 1e-12f);
}

__global__ void k_final(const int* __restrict__ rows, const int* __restrict__ cols,
                        const float* __restrict__ vals, const u32* __restrict__ mbits,
                        const float* __restrict__ dinv, const u32* __restrict__ scalars,
                        float* __restrict__ out) {
  u32 anyAlive = scalars[7];
  int stride = gridDim.x * blockDim.x * 4;
  for (int e0 = (blockIdx.x * blockDim.x + threadIdx.x) * 4; e0 < N_EDGES; e0 += stride) {
    u32 q = (mbits[e0 >> 5] >> (e0 & 31)) & 0xFu;
    int4 r4 = *reinterpret_cast<const int4*>(rows + e0);
    int4 c4 = *reinterpret_cast<const int4*>(cols + e0);
    const int rr[4] = {r4.x, r4.y, r4.z, r4.w};
    const int cc[4] = {c4.x, c4.y, c4.z, c4.w};
    float4 enc, msk;
    float ev[4], mv[4];
#pragma unroll
    for (int j = 0; j < 4; j++) {
      u32 mb = (q >> j) & 1u;
      float nv = 0.0f;
      if (!mb) nv = dinv[rr[j]] * dinv[cc[j]];
      ev[j] = nv;
      mv[j] = mb ? 1.0f : 0.0f;
    }
    if (!anyAlive) {                 // uniform cold path: fall back to original vals
      float4 v4 = *reinterpret_cast<const float4*>(vals + e0);
      ev[0] = v4.x; ev[1] = v4.y; ev[2] = v4.z; ev[3] = v4.w;
    }
    enc.x = ev[0]; enc.y = ev[1]; enc.z = ev[2]; enc.w = ev[3];
    msk.x = mv[0]; msk.y = mv[1]; msk.z = mv[2]; msk.w = mv[3];
    *reinterpret_cast<float4*>(out + e0)            = enc;
    *reinterpret_cast<float4*>(out + N_EDGES + e0)  = msk;
  }
}

extern "C" void kernel_launch(void* const* d_in, const int* in_sizes, int n_in,
                              void* d_out, int out_size, void* d_ws, size_t ws_size,
                              hipStream_t stream) {
  const int*   rows  = (const int*)d_in[0];
  const int*   cols  = (const int*)d_in[1];
  const float* vals  = (const float*)d_in[2];
  const int*   seeds = (const int*)d_in[3];
  int n_seeds = in_sizes[3];
  float* out = (float*)d_out;

  if (ws_size < WS_NEED) return;

  char* ws = (char*)d_ws;
  u32*   mbits  = (u32*)(ws + OFF_MBITS);
  u32*   seedb  = (u32*)(ws + OFF_SEEDB);
  u8*    cand   = (u8*)(ws + OFF_CAND);
  u32*   mvals  = (u32*)(ws + OFF_MVALS);
  float* deg    = (float*)(ws + OFF_DEG);
  u32*   hist1  = (u32*)(ws + OFF_HIST1);
  u32*   hist2  = (u32*)(ws + OFF_HIST2);
  u32*   tiebuf = (u32*)(ws + OFF_TIEBUF);
  u32*   scal   = (u32*)(ws + OFF_SCAL);

  // ----- host-side key derivation: key = jax.random.key(42) = (0, 42); two splits -----
  u32 sub[2][2];
  u32 ka = 0u, kb = 42u;
  for (int i = 0; i < 2; i++) {
#if TF_PARTITIONABLE
    u32 nk0, nk1, sa, sb_;
    tf2x32(ka, kb, 0u, 0u, nk0, nk1);
    tf2x32(ka, kb, 0u, 1u, sa, sb_);
    sub[i][0] = sa; sub[i][1] = sb_;
    ka = nk0; kb = nk1;
#else
    u32 a0, a1, b0, b1;
    tf2x32(ka, kb, 0u, 2u, a0, a1);
    tf2x32(ka, kb, 1u, 3u, b0, b1);
    sub[i][0] = a1; sub[i][1] = b1;
    ka = a0; kb = b0;
#endif
  }

  hipMemsetAsync(ws, 0, WS_NEED, stream);
  k_scatter_seeds<<<(n_seeds + BLK - 1) / BLK, BLK, 0, stream>>>(seeds, n_seeds, seedb);

  for (int i = 0; i < MASK_DEPTH; i++) {
    if (i > 0) {
      hipMemsetAsync(cand, 0, N_NODES, stream);
      hipMemsetAsync(ws + OFF_HIST1, 0, WS_NEED - OFF_HIST1, stream);
    }
    int do_cand = (i != MASK_DEPTH - 1);
    k_mark<<<MARK_GRID, MARK_BLK, 0, stream>>>(rows, cols, mbits, seedb, cand, do_cand);
    if (!do_cand) break;
    k_count_cand<<<NODE_GRID, BLK, 0, stream>>>(cand, scal);
    k_mvals_hist1<<<NODE_GRID, BLK, 0, stream>>>(sub[i][0], sub[i][1], cand, mvals, hist1);
    k_find_bucket<4096><<<1, BLK, 0, stream>>>(hist1, scal, 0, i + 1);
    k_hist2<<<NODE_GRID, BLK, 0, stream>>>(cand, mvals, scal, hist2);
    k_find_bucket<2048><<<1, BLK, 0, stream>>>(hist2, scal, 1, 0);
    hipMemsetAsync(seedb, 0, SEED_WORDS * sizeof(u32), stream);   // full-replacement semantics
    k_select<<<NODE_GRID, BLK, 0, stream>>>(cand, mvals, scal, seedb, tiebuf);
    k_ties<<<1, BLK, 0, stream>>>(scal, tiebuf, seedb);
  }

  k_deg<<<EDGE_GRID, BLK, 0, stream>>>(rows, mbits, deg, scal);
  k_dinv<<<(N_NODES + BLK - 1) / BLK, BLK, 0, stream>>>(deg);
  k_final<<<EDGE_GRID, BLK, 0, stream>>>(rows, cols, vals, mbits, deg, scal, out);
}

// Round 3
// 897.767 us; speedup vs baseline: 1.7266x; 1.1813x over previous
//
#include <hip/hip_runtime.h>
#include <stdint.h>

typedef unsigned int u32;
typedef unsigned char u8;

#define N_NODES 500000
#define N_EDGES 16000000
#define MASK_DEPTH 3
#define BLK 256
#define EDGE_GRID 2048
#define NODE_GRID 1024
#define TIE_CAP 8192
#define SEED_WORDS 15625           // ceil(500000/32)
#define MARK_BLK 512
#define MARK_GRID 512              // 2 blocks/CU x 256 CUs

// degree-count privatization
#define DEG_BLK 512
#define DEG_GRID 512               // 8 groups x 64 blocks; 2 blocks/CU
#define NGROUPS 8
#define NPG 62500                  // nodes per group (500000/8)
#define WPG 15625                  // u32 words per group (4 packed u8 each)

#define TF_PARTITIONABLE 1

// ---------------- workspace layout (bytes) ----------------
#define OFF_MBITS   0u             // u32[N_EDGES/32]   = 2,000,000 B
#define OFF_SEEDB   2000000u       // u32[SEED_WORDS]   =    62,500 B (+pad)
#define OFF_CAND    2062528u       // u8[N_NODES]       =   500,000 B
#define OFF_MVALS   2562528u       // u32[N_NODES]      = 2,000,000 B (reused as dinv after loop)
#define OFF_DEG     4562528u       // u32[WPG*NGROUPS]  =   500,000 B packed u8 degree counts
#define OFF_HIST1   6562528u       // u32[4096]
#define OFF_HIST2   6578912u       // u32[2048]
#define OFF_TIEBUF  6587104u       // u32[TIE_CAP]
#define OFF_SCAL    6619872u       // u32[64]
#define WS_NEED     6620128u
// scalars: [0]=n_cand [1]=keep_num [2]=b* [3]=rem1 [4]=m* [5]=rem2 [6]=tie_count [7]=any_alive [8]=valid

// Threefry-2x32, 20 rounds (exactly JAX's threefry2x32_p)
__host__ __device__ inline void tf2x32(u32 k0, u32 k1, u32 x0, u32 x1, u32& o0, u32& o1) {
  u32 ks0 = k0, ks1 = k1, ks2 = k0 ^ k1 ^ 0x1BD11BDAu;
  x0 += ks0; x1 += ks1;
#define TFR(r) { x0 += x1; x1 = (x1 << (r)) | (x1 >> (32 - (r))); x1 ^= x0; }
  TFR(13) TFR(15) TFR(26) TFR(6)   x0 += ks1; x1 += ks2 + 1u;
  TFR(17) TFR(29) TFR(16) TFR(24)  x0 += ks2; x1 += ks0 + 2u;
  TFR(13) TFR(15) TFR(26) TFR(6)   x0 += ks0; x1 += ks1 + 3u;
  TFR(17) TFR(29) TFR(16) TFR(24)  x0 += ks1; x1 += ks2 + 4u;
  TFR(13) TFR(15) TFR(26) TFR(6)   x0 += ks2; x1 += ks0 + 5u;
#undef TFR
  o0 = x0; o1 = x1;
}

__global__ void k_scatter_seeds(const int* __restrict__ seeds, int ns, u32* __restrict__ seedbits) {
  int i = blockIdx.x * blockDim.x + threadIdx.x;
  if (i < ns) {
    int v = seeds[i];
    atomicOr(&seedbits[v >> 5], 1u << (v & 31));
  }
}

// Edges touching seeds -> mask bit; endpoints of newly masked edges -> cand.
// Seed membership staged as a 62.5KB bitset in LDS (2 blocks/CU).
__global__ __launch_bounds__(MARK_BLK) void
k_mark(const int* __restrict__ rows, const int* __restrict__ cols,
       u32* __restrict__ mbits, const u32* __restrict__ seedbits,
       u8* __restrict__ cand, int do_cand) {
  __shared__ u32 sb[SEED_WORDS];
  for (int w = threadIdx.x; w < SEED_WORDS; w += MARK_BLK) sb[w] = seedbits[w];
  __syncthreads();
  int stride = gridDim.x * blockDim.x * 4;
  for (int e0 = (blockIdx.x * blockDim.x + threadIdx.x) * 4; e0 < N_EDGES; e0 += stride) {
    u32 mw = mbits[e0 >> 5];
    u32 q  = (mw >> (e0 & 31)) & 0xFu;           // masked-bits of this quad
    if (q == 0xFu) continue;                     // whole quad already masked
    int4 r4 = *reinterpret_cast<const int4*>(rows + e0);
    int4 c4 = *reinterpret_cast<const int4*>(cols + e0);
    u32 newm = 0;
    const int rr[4] = {r4.x, r4.y, r4.z, r4.w};
    const int cc[4] = {c4.x, c4.y, c4.z, c4.w};
#pragma unroll
    for (int j = 0; j < 4; j++) {
      if ((q >> j) & 1u) continue;
      int r = rr[j], c = cc[j];
      u32 hr = (sb[r >> 5] >> (r & 31)) & 1u;
      u32 hc = (sb[c >> 5] >> (c & 31)) & 1u;
      if (hr | hc) {
        newm |= 1u << ((e0 & 31) + j);
        if (do_cand) { cand[r] = 1; cand[c] = 1; }
      }
    }
    if (newm) atomicOr(&mbits[e0 >> 5], newm);
  }
}

__global__ void k_count_cand(const u8* __restrict__ cand, u32* __restrict__ scalars) {
  __shared__ u32 red[BLK];
  u32 s = 0;
  int stride = gridDim.x * blockDim.x;
  for (int v = blockIdx.x * blockDim.x + threadIdx.x; v < N_NODES; v += stride) s += cand[v];
  red[threadIdx.x] = s; __syncthreads();
  for (int o = BLK / 2; o > 0; o >>= 1) {
    if (threadIdx.x < (u32)o) red[threadIdx.x] += red[threadIdx.x + o];
    __syncthreads();
  }
  if (threadIdx.x == 0) atomicAdd(&scalars[0], red[0]);
}

// Per-node uniform bits (top 23 bits rank-determining) + coarse histogram over candidates.
__global__ void k_mvals_hist1(u32 s0, u32 s1, const u8* __restrict__ cand,
                              u32* __restrict__ mvals, u32* __restrict__ hist1) {
#if TF_PARTITIONABLE
  int stride = gridDim.x * blockDim.x;
  for (int v = blockIdx.x * blockDim.x + threadIdx.x; v < N_NODES; v += stride) {
    u32 a, b; tf2x32(s0, s1, 0u, (u32)v, a, b);
    u32 m = (a ^ b) >> 9;
    mvals[v] = m;
    if (cand[v]) atomicAdd(&hist1[m >> 11], 1u);
  }
#else
  const int H = N_NODES / 2;
  int stride = gridDim.x * blockDim.x;
  for (int j = blockIdx.x * blockDim.x + threadIdx.x; j < H; j += stride) {
    u32 a, b; tf2x32(s0, s1, (u32)j, (u32)(j + H), a, b);
    u32 m0 = a >> 9, m1 = b >> 9;
    mvals[j] = m0; mvals[j + H] = m1;
    if (cand[j])     atomicAdd(&hist1[m0 >> 11], 1u);
    if (cand[j + H]) atomicAdd(&hist1[m1 >> 11], 1u);
  }
#endif
}

// Single block: find bucket containing the K-th smallest; write bucket + remainder.
template <int NB>
__global__ void k_find_bucket(const u32* __restrict__ hist, u32* __restrict__ scalars,
                              int stage, int shift) {
  __shared__ u32 warpsum[BLK / 64];
  int tid = threadIdx.x;
  u32 K, valid;
  if (stage == 0) {
    u32 nc = scalars[0];
    K = nc >> shift;                       // == floor(n_cand * 0.5^(i+1)) exactly
    valid = (K > 0) ? 1u : 0u;
    if (tid == 0) { scalars[1] = K; scalars[8] = valid; }
  } else {
    valid = scalars[8];
    K = scalars[3];
  }
  if (!valid) return;
  constexpr int CH = NB / BLK;
  u32 loc[CH];
  u32 s = 0;
  int base = tid * CH;
#pragma unroll
  for (int i = 0; i < CH; i++) { loc[i] = hist[base + i]; s += loc[i]; }
  u32 x = s;
  for (int off = 1; off < 64; off <<= 1) {
    u32 y = __shfl_up(x, off, 64);
    if ((tid & 63) >= off) x += y;
  }
  if ((tid & 63) == 63) warpsum[tid >> 6] = x;
  __syncthreads();
  u32 woff = 0;
  for (int w = 0; w < (tid >> 6); w++) woff += warpsum[w];
  u32 run = woff + x - s;
#pragma unroll
  for (int i = 0; i < CH; i++) {
    u32 h = loc[i];
    if (h && K > run && K <= run + h) {
      if (stage == 0) { scalars[2] = (u32)(base + i); scalars[3] = K - run; }
      else            { scalars[4] = (scalars[2] << 11) | (u32)(base + i); scalars[5] = K - run; }
    }
    run += h;
  }
}

__global__ void k_hist2(const u8* __restrict__ cand, const u32* __restrict__ mvals,
                        const u32* __restrict__ scalars, u32* __restrict__ hist2) {
  if (!scalars[8]) return;
  u32 bstar = scalars[2];
  int stride = gridDim.x * blockDim.x;
  for (int v = blockIdx.x * blockDim.x + threadIdx.x; v < N_NODES; v += stride) {
    if (cand[v]) {
      u32 m = mvals[v];
      if ((m >> 11) == bstar) atomicAdd(&hist2[m & 2047u], 1u);
    }
  }
}

// seedbits must be zeroed before this (full-replacement semantics).
__global__ void k_select(const u8* __restrict__ cand, const u32* __restrict__ mvals,
                         u32* __restrict__ scalars, u32* __restrict__ seedbits,
                         u32* __restrict__ tiebuf) {
  if (!scalars[8]) return;
  u32 mstar = scalars[4];
  int stride = gridDim.x * blockDim.x;
  for (int v = blockIdx.x * blockDim.x + threadIdx.x; v < N_NODES; v += stride) {
    if (cand[v]) {
      u32 m = mvals[v];
      if (m < mstar) atomicOr(&seedbits[v >> 5], 1u << (v & 31));
      else if (m == mstar) {
        u32 p = atomicAdd(&scalars[6], 1u);
        if (p < TIE_CAP) tiebuf[p] = (u32)v;
      }
    }
  }
}

// Stable tie-break: among nodes with m == m*, keep the rem2 smallest node indices.
__global__ void k_ties(u32* __restrict__ scalars, const u32* __restrict__ tiebuf,
                       u32* __restrict__ seedbits) {
  if (!scalars[8]) return;
  u32 T = scalars[6]; if (T > TIE_CAP) T = TIE_CAP;
  u32 rem2 = scalars[5];
  for (u32 i = threadIdx.x; i < T; i += blockDim.x) {
    u32 v = tiebuf[i];
    u32 rank = 0;
    for (u32 j = 0; j < T; j++) rank += (tiebuf[j] < v) ? 1u : 0u;
    if (rank < rem2) atomicOr(&seedbits[v >> 5], 1u << (v & 31));
  }
}

// Privatized degree count: 8 node-groups; each block owns one group's 62.5K nodes
// as packed-u8 LDS counters (max row degree ~75 << 255, cross-block field sums too).
// Flush = coalesced u32 atomics of 4-packed fields.
__global__ __launch_bounds__(DEG_BLK) void
k_deg_lds(const int* __restrict__ rows, const u32* __restrict__ mbits,
          u32* __restrict__ degp, u32* __restrict__ scalars) {
  __shared__ u32 lcnt[WPG];
  int group = blockIdx.x & (NGROUPS - 1);
  int bsub  = blockIdx.x >> 3;               // 64 blocks per group
  int lo = group * NPG;
  for (int w = threadIdx.x; w < WPG; w += DEG_BLK) lcnt[w] = 0;
  __syncthreads();
  int any = 0;
  const int stride = (DEG_GRID / NGROUPS) * DEG_BLK * 4;
  for (int e0 = (bsub * DEG_BLK + threadIdx.x) * 4; e0 < N_EDGES; e0 += stride) {
    u32 q = (mbits[e0 >> 5] >> (e0 & 31)) & 0xFu;
    if (q == 0xFu) continue;
    int4 r4 = *reinterpret_cast<const int4*>(rows + e0);
    const int rr[4] = {r4.x, r4.y, r4.z, r4.w};
#pragma unroll
    for (int j = 0; j < 4; j++) {
      if (!((q >> j) & 1u)) {
        any = 1;
        u32 r = (u32)(rr[j] - lo);
        if (r < (u32)NPG) atomicAdd(&lcnt[r >> 2], 1u << ((r & 3u) * 8u));
      }
    }
  }
  __syncthreads();
  for (int w = threadIdx.x; w < WPG; w += DEG_BLK) {
    u32 c = lcnt[w];
    if (c) atomicAdd(&degp[group * WPG + w], c);
  }
  if (any) scalars[7] = 1u;   // benign same-value race; kernel-end release makes it visible
}

// packed u8 counts -> dinv floats (float4 store per word)
__global__ void k_dinv2(const u32* __restrict__ degp, float* __restrict__ dinv) {
  int w = blockIdx.x * blockDim.x + threadIdx.x;
  if (w < WPG * NGROUPS) {
    u32 c = degp[w];
    float4 o;
    o.x = 1.0f / sqrtf((float)(c & 0xFFu) + 1e-12f);
    o.y = 1.0f / sqrtf((float)((c >> 8) & 0xFFu) + 1e-12f);
    o.z = 1.0f / sqrtf((float)((c >> 16) & 0xFFu) + 1e-12f);
    o.w = 1.0f / sqrtf((float)((c >> 24) & 0xFFu) + 1e-12f);
    *reinterpret_cast<float4*>(dinv + w * 4) = o;
  }
}

__global__ void k_final(const int* __restrict__ rows, const int* __restrict__ cols,
                        const float* __restrict__ vals, const u32* __restrict__ mbits,
                        const float* __restrict__ dinv, const u32* __restrict__ scalars,
                        float* __restrict__ out) {
  u32 anyAlive = scalars[7];
  int stride = gridDim.x * blockDim.x * 4;
  for (int e0 = (blockIdx.x * blockDim.x + threadIdx.x) * 4; e0 < N_EDGES; e0 += stride) {
    u32 q = (mbits[e0 >> 5] >> (e0 & 31)) & 0xFu;
    int4 r4 = *reinterpret_cast<const int4*>(rows + e0);
    int4 c4 = *reinterpret_cast<const int4*>(cols + e0);
    const int rr[4] = {r4.x, r4.y, r4.z, r4.w};
    const int cc[4] = {c4.x, c4.y, c4.z, c4.w};
    float4 enc, msk;
    float ev[4], mv[4];
#pragma unroll
    for (int j = 0; j < 4; j++) {
      u32 mb = (q >> j) & 1u;
      float nv = 0.0f;
      if (!mb) nv = dinv[rr[j]] * dinv[cc[j]];
      ev[j] = nv;
      mv[j] = mb ? 1.0f : 0.0f;
    }
    if (!anyAlive) {
      float4 v4 = *reinterpret_cast<const float4*>(vals + e0);
      ev[0] = v4.x; ev[1] = v4.y; ev[2] = v4.z; ev[3] = v4.w;
    }
    enc.x = ev[0]; enc.y = ev[1]; enc.z = ev[2]; enc.w = ev[3];
    msk.x = mv[0]; msk.y = mv[1]; msk.z = mv[2]; msk.w = mv[3];
    *reinterpret_cast<float4*>(out + e0)            = enc;
    *reinterpret_cast<float4*>(out + N_EDGES + e0)  = msk;
  }
}

extern "C" void kernel_launch(void* const* d_in, const int* in_sizes, int n_in,
                              void* d_out, int out_size, void* d_ws, size_t ws_size,
                              hipStream_t stream) {
  const int*   rows  = (const int*)d_in[0];
  const int*   cols  = (const int*)d_in[1];
  const float* vals  = (const float*)d_in[2];
  const int*   seeds = (const int*)d_in[3];
  int n_seeds = in_sizes[3];
  float* out = (float*)d_out;

  if (ws_size < WS_NEED) return;

  char* ws = (char*)d_ws;
  u32*   mbits  = (u32*)(ws + OFF_MBITS);
  u32*   seedb  = (u32*)(ws + OFF_SEEDB);
  u8*    cand   = (u8*)(ws + OFF_CAND);
  u32*   mvals  = (u32*)(ws + OFF_MVALS);
  u32*   degp   = (u32*)(ws + OFF_DEG);
  float* dinv   = (float*)(ws + OFF_MVALS);   // mvals retired after the mask loop
  u32*   hist1  = (u32*)(ws + OFF_HIST1);
  u32*   hist2  = (u32*)(ws + OFF_HIST2);
  u32*   tiebuf = (u32*)(ws + OFF_TIEBUF);
  u32*   scal   = (u32*)(ws + OFF_SCAL);

  // ----- host-side key derivation: key = jax.random.key(42) = (0, 42); two splits -----
  u32 sub[2][2];
  u32 ka = 0u, kb = 42u;
  for (int i = 0; i < 2; i++) {
#if TF_PARTITIONABLE
    u32 nk0, nk1, sa, sb_;
    tf2x32(ka, kb, 0u, 0u, nk0, nk1);
    tf2x32(ka, kb, 0u, 1u, sa, sb_);
    sub[i][0] = sa; sub[i][1] = sb_;
    ka = nk0; kb = nk1;
#else
    u32 a0, a1, b0, b1;
    tf2x32(ka, kb, 0u, 2u, a0, a1);
    tf2x32(ka, kb, 1u, 3u, b0, b1);
    sub[i][0] = a1; sub[i][1] = b1;
    ka = a0; kb = b0;
#endif
  }

  hipMemsetAsync(ws, 0, WS_NEED, stream);
  k_scatter_seeds<<<(n_seeds + BLK - 1) / BLK, BLK, 0, stream>>>(seeds, n_seeds, seedb);

  for (int i = 0; i < MASK_DEPTH; i++) {
    if (i > 0) {
      hipMemsetAsync(cand, 0, N_NODES, stream);
      hipMemsetAsync(ws + OFF_HIST1, 0, WS_NEED - OFF_HIST1, stream);
    }
    int do_cand = (i != MASK_DEPTH - 1);
    k_mark<<<MARK_GRID, MARK_BLK, 0, stream>>>(rows, cols, mbits, seedb, cand, do_cand);
    if (!do_cand) break;
    k_count_cand<<<NODE_GRID, BLK, 0, stream>>>(cand, scal);
    k_mvals_hist1<<<NODE_GRID, BLK, 0, stream>>>(sub[i][0], sub[i][1], cand, mvals, hist1);
    k_find_bucket<4096><<<1, BLK, 0, stream>>>(hist1, scal, 0, i + 1);
    k_hist2<<<NODE_GRID, BLK, 0, stream>>>(cand, mvals, scal, hist2);
    k_find_bucket<2048><<<1, BLK, 0, stream>>>(hist2, scal, 1, 0);
    hipMemsetAsync(seedb, 0, SEED_WORDS * sizeof(u32), stream);   // full-replacement semantics
    k_select<<<NODE_GRID, BLK, 0, stream>>>(cand, mvals, scal, seedb, tiebuf);
    k_ties<<<1, BLK, 0, stream>>>(scal, tiebuf, seedb);
  }

  k_deg_lds<<<DEG_GRID, DEG_BLK, 0, stream>>>(rows, mbits, degp, scal);
  k_dinv2<<<(WPG * NGROUPS + BLK - 1) / BLK, BLK, 0, stream>>>(degp, dinv);
  k_final<<<EDGE_GRID, BLK, 0, stream>>>(rows, cols, vals, mbits, dinv, scal, out);
}

// Round 6
// 848.473 us; speedup vs baseline: 1.8269x; 1.0581x over previous
//
#include <hip/hip_runtime.h>
#include <stdint.h>

typedef unsigned int u32;
typedef unsigned char u8;

#define N_NODES 500000
#define N_EDGES 16000000
#define NWORDS_E 500000            // N_EDGES / 32
#define MASK_DEPTH 3
#define BLK 256
#define EDGE_GRID 2048
#define NODE_GRID 1024
#define TIE_CAP 8192
#define SEED_WORDS 15625           // ceil(500000/32)

// k_mark2: word-owned mask update, LDS seed+cand bitsets
#define MARK_BLK 1024
#define MARK_GRID_CAND 256         // 1 block/CU (125KB LDS)
#define MARK_GRID_LAST 512         // 2 blocks/CU (62.5KB LDS)

// degree-count privatization
#define DEG_BLK 512
#define DEG_GRID 512               // 8 groups x 64 blocks; 2 blocks/CU
#define NGROUPS 8
#define NPG 62500                  // nodes per group (500000/8)
#define WPG 15625                  // u32 words per group (4 packed u8 each)

#define TF_PARTITIONABLE 1

// ---------------- workspace layout (bytes) ----------------
#define OFF_MBITS   0u             // u32[NWORDS_E]     = 2,000,000 B
#define OFF_SEEDB   2000000u       // u32[SEED_WORDS]   =    62,500 B (+pad)
#define OFF_CANDB   2062528u       // u32[SEED_WORDS]   =    62,500 B (+pad)
#define OFF_MVALS   2125056u       // u32[N_NODES]      = 2,000,000 B (reused as dinv after loop)
#define OFF_DEG     4125056u       // u32[WPG*NGROUPS]  =   500,000 B packed u8 degree counts
#define OFF_HIST1   4625056u       // u32[4096]
#define OFF_HIST2   4641440u       // u32[2048]
#define OFF_TIEBUF  4649632u       // u32[TIE_CAP]
#define OFF_SCAL    4682400u       // u32[64]
#define WS_NEED     4682656u
// scalars: [0]=n_cand [1]=keep_num [2]=b* [3]=rem1 [4]=m* [5]=rem2 [6]=tie_count [7]=any_alive [8]=valid

// Threefry-2x32, 20 rounds (exactly JAX's threefry2x32_p)
__host__ __device__ inline void tf2x32(u32 k0, u32 k1, u32 x0, u32 x1, u32& o0, u32& o1) {
  u32 ks0 = k0, ks1 = k1, ks2 = k0 ^ k1 ^ 0x1BD11BDAu;
  x0 += ks0; x1 += ks1;
#define TFR(r) { x0 += x1; x1 = (x1 << (r)) | (x1 >> (32 - (r))); x1 ^= x0; }
  TFR(13) TFR(15) TFR(26) TFR(6)   x0 += ks1; x1 += ks2 + 1u;
  TFR(17) TFR(29) TFR(16) TFR(24)  x0 += ks2; x1 += ks0 + 2u;
  TFR(13) TFR(15) TFR(26) TFR(6)   x0 += ks0; x1 += ks1 + 3u;
  TFR(17) TFR(29) TFR(16) TFR(24)  x0 += ks1; x1 += ks2 + 4u;
  TFR(13) TFR(15) TFR(26) TFR(6)   x0 += ks2; x1 += ks0 + 5u;
#undef TFR
  o0 = x0; o1 = x1;
}

__global__ void k_scatter_seeds(const int* __restrict__ seeds, int ns, u32* __restrict__ seedbits) {
  int i = blockIdx.x * blockDim.x + threadIdx.x;
  if (i < ns) {
    int v = seeds[i];
    atomicOr(&seedbits[v >> 5], 1u << (v & 31));
  }
}

// Word-owned marking: thread owns one 32-edge mbits word -> plain store, no atomics.
// Seed bitset in LDS; cand bitset privatized in LDS (dedup), coalesced atomicOr flush.
template <int DO_CAND>
__global__ __launch_bounds__(MARK_BLK) void
k_mark2(const int* __restrict__ rows, const int* __restrict__ cols,
        u32* __restrict__ mbits, const u32* __restrict__ seedbits,
        u32* __restrict__ candb) {
  __shared__ u32 sb[SEED_WORDS];
  __shared__ u32 cb[DO_CAND ? SEED_WORDS : 4];
  for (int w = threadIdx.x; w < SEED_WORDS; w += MARK_BLK) {
    sb[w] = seedbits[w];
    if (DO_CAND) cb[w] = 0;
  }
  __syncthreads();
  const int stride = gridDim.x * blockDim.x;
  for (int w0 = blockIdx.x * blockDim.x + threadIdx.x; w0 < NWORDS_E; w0 += stride) {
    u32 mw = mbits[w0];
    if (mw == 0xFFFFFFFFu) continue;          // whole word already masked
    const int e0 = w0 * 32;
    u32 newm = 0;
#pragma unroll
    for (int g = 0; g < 8; g++) {
      u32 q = (mw >> (g * 4)) & 0xFu;
      if (q == 0xFu) continue;
      int4 r4 = *reinterpret_cast<const int4*>(rows + e0 + g * 4);
      int4 c4 = *reinterpret_cast<const int4*>(cols + e0 + g * 4);
      const int rr[4] = {r4.x, r4.y, r4.z, r4.w};
      const int cc[4] = {c4.x, c4.y, c4.z, c4.w};
#pragma unroll
      for (int j = 0; j < 4; j++) {
        if ((q >> j) & 1u) continue;
        int r = rr[j], c = cc[j];
        u32 hr = (sb[r >> 5] >> (r & 31)) & 1u;
        u32 hc = (sb[c >> 5] >> (c & 31)) & 1u;
        if (hr | hc) {
          newm |= 1u << (g * 4 + j);
          if (DO_CAND) {
            atomicOr(&cb[r >> 5], 1u << (r & 31));
            atomicOr(&cb[c >> 5], 1u << (c & 31));
          }
        }
      }
    }
    if (newm) mbits[w0] = mw | newm;          // word owned exclusively: plain store
  }
  if (DO_CAND) {
    __syncthreads();
    for (int w = threadIdx.x; w < SEED_WORDS; w += MARK_BLK) {
      u32 c = cb[w];
      if (c) atomicOr(&candb[w], c);
    }
  }
}

__global__ void k_count_cand(const u32* __restrict__ candb, u32* __restrict__ scalars) {
  __shared__ u32 red[BLK];
  u32 s = 0;
  int stride = gridDim.x * blockDim.x;
  for (int w = blockIdx.x * blockDim.x + threadIdx.x; w < SEED_WORDS; w += stride)
    s += (u32)__popc(candb[w]);
  red[threadIdx.x] = s; __syncthreads();
  for (int o = BLK / 2; o > 0; o >>= 1) {
    if (threadIdx.x < (u32)o) red[threadIdx.x] += red[threadIdx.x + o];
    __syncthreads();
  }
  if (threadIdx.x == 0) atomicAdd(&scalars[0], red[0]);
}

// Per-node uniform bits (top 23 bits rank-determining) + coarse histogram over candidates.
__global__ void k_mvals_hist1(u32 s0, u32 s1, const u32* __restrict__ candb,
                              u32* __restrict__ mvals, u32* __restrict__ hist1) {
#if TF_PARTITIONABLE
  int stride = gridDim.x * blockDim.x;
  for (int v = blockIdx.x * blockDim.x + threadIdx.x; v < N_NODES; v += stride) {
    u32 a, b; tf2x32(s0, s1, 0u, (u32)v, a, b);
    u32 m = (a ^ b) >> 9;
    mvals[v] = m;
    if ((candb[v >> 5] >> (v & 31)) & 1u) atomicAdd(&hist1[m >> 11], 1u);
  }
#else
  const int H = N_NODES / 2;
  int stride = gridDim.x * blockDim.x;
  for (int j = blockIdx.x * blockDim.x + threadIdx.x; j < H; j += stride) {
    u32 a, b; tf2x32(s0, s1, (u32)j, (u32)(j + H), a, b);
    u32 m0 = a >> 9, m1 = b >> 9;
    mvals[j] = m0; mvals[j + H] = m1;
    if ((candb[j >> 5] >> (j & 31)) & 1u)                 atomicAdd(&hist1[m0 >> 11], 1u);
    if ((candb[(j + H) >> 5] >> ((j + H) & 31)) & 1u)     atomicAdd(&hist1[m1 >> 11], 1u);
  }
#endif
}

// Single block: find bucket containing the K-th smallest; write bucket + remainder.
template <int NB>
__global__ void k_find_bucket(const u32* __restrict__ hist, u32* __restrict__ scalars,
                              int stage, int shift) {
  __shared__ u32 warpsum[BLK / 64];
  int tid = threadIdx.x;
  u32 K, valid;
  if (stage == 0) {
    u32 nc = scalars[0];
    K = nc >> shift;                       // == floor(n_cand * 0.5^(i+1)) exactly
    valid = (K > 0) ? 1u : 0u;
    if (tid == 0) { scalars[1] = K; scalars[8] = valid; }
  } else {
    valid = scalars[8];
    K = scalars[3];
  }
  if (!valid) return;
  constexpr int CH = NB / BLK;
  u32 loc[CH];
  u32 s = 0;
  int base = tid * CH;
#pragma unroll
  for (int i = 0; i < CH; i++) { loc[i] = hist[base + i]; s += loc[i]; }
  u32 x = s;
  for (int off = 1; off < 64; off <<= 1) {
    u32 y = __shfl_up(x, off, 64);
    if ((tid & 63) >= off) x += y;
  }
  if ((tid & 63) == 63) warpsum[tid >> 6] = x;
  __syncthreads();
  u32 woff = 0;
  for (int w = 0; w < (tid >> 6); w++) woff += warpsum[w];
  u32 run = woff + x - s;
#pragma unroll
  for (int i = 0; i < CH; i++) {
    u32 h = loc[i];
    if (h && K > run && K <= run + h) {
      if (stage == 0) { scalars[2] = (u32)(base + i); scalars[3] = K - run; }
      else            { scalars[4] = (scalars[2] << 11) | (u32)(base + i); scalars[5] = K - run; }
    }
    run += h;
  }
}

__global__ void k_hist2(const u32* __restrict__ candb, const u32* __restrict__ mvals,
                        const u32* __restrict__ scalars, u32* __restrict__ hist2) {
  if (!scalars[8]) return;
  u32 bstar = scalars[2];
  int stride = gridDim.x * blockDim.x;
  for (int v = blockIdx.x * blockDim.x + threadIdx.x; v < N_NODES; v += stride) {
    if ((candb[v >> 5] >> (v & 31)) & 1u) {
      u32 m = mvals[v];
      if ((m >> 11) == bstar) atomicAdd(&hist2[m & 2047u], 1u);
    }
  }
}

// seedbits must be zeroed before this (full-replacement semantics).
__global__ void k_select(const u32* __restrict__ candb, const u32* __restrict__ mvals,
                         u32* __restrict__ scalars, u32* __restrict__ seedbits,
                         u32* __restrict__ tiebuf) {
  if (!scalars[8]) return;
  u32 mstar = scalars[4];
  int stride = gridDim.x * blockDim.x;
  for (int v = blockIdx.x * blockDim.x + threadIdx.x; v < N_NODES; v += stride) {
    if ((candb[v >> 5] >> (v & 31)) & 1u) {
      u32 m = mvals[v];
      if (m < mstar) atomicOr(&seedbits[v >> 5], 1u << (v & 31));
      else if (m == mstar) {
        u32 p = atomicAdd(&scalars[6], 1u);
        if (p < TIE_CAP) tiebuf[p] = (u32)v;
      }
    }
  }
}

// Stable tie-break: among nodes with m == m*, keep the rem2 smallest node indices.
__global__ void k_ties(u32* __restrict__ scalars, const u32* __restrict__ tiebuf,
                       u32* __restrict__ seedbits) {
  if (!scalars[8]) return;
  u32 T = scalars[6]; if (T > TIE_CAP) T = TIE_CAP;
  u32 rem2 = scalars[5];
  for (u32 i = threadIdx.x; i < T; i += blockDim.x) {
    u32 v = tiebuf[i];
    u32 rank = 0;
    for (u32 j = 0; j < T; j++) rank += (tiebuf[j] < v) ? 1u : 0u;
    if (rank < rem2) atomicOr(&seedbits[v >> 5], 1u << (v & 31));
  }
}

// Privatized degree count: 8 node-groups; each block owns one group's 62.5K nodes
// as packed-u8 LDS counters (max row degree ~75 << 255, cross-block field sums too).
__global__ __launch_bounds__(DEG_BLK) void
k_deg_lds(const int* __restrict__ rows, const u32* __restrict__ mbits,
          u32* __restrict__ degp, u32* __restrict__ scalars) {
  __shared__ u32 lcnt[WPG];
  int group = blockIdx.x & (NGROUPS - 1);
  int bsub  = blockIdx.x >> 3;               // 64 blocks per group
  int lo = group * NPG;
  for (int w = threadIdx.x; w < WPG; w += DEG_BLK) lcnt[w] = 0;
  __syncthreads();
  int any = 0;
  const int stride = (DEG_GRID / NGROUPS) * DEG_BLK * 4;
  for (int e0 = (bsub * DEG_BLK + threadIdx.x) * 4; e0 < N_EDGES; e0 += stride) {
    u32 q = (mbits[e0 >> 5] >> (e0 & 31)) & 0xFu;
    if (q == 0xFu) continue;
    int4 r4 = *reinterpret_cast<const int4*>(rows + e0);
    const int rr[4] = {r4.x, r4.y, r4.z, r4.w};
#pragma unroll
    for (int j = 0; j < 4; j++) {
      if (!((q >> j) & 1u)) {
        any = 1;
        u32 r = (u32)(rr[j] - lo);
        if (r < (u32)NPG) atomicAdd(&lcnt[r >> 2], 1u << ((r & 3u) * 8u));
      }
    }
  }
  __syncthreads();
  for (int w = threadIdx.x; w < WPG; w += DEG_BLK) {
    u32 c = lcnt[w];
    if (c) atomicAdd(&degp[group * WPG + w], c);
  }
  if (any) scalars[7] = 1u;   // benign same-value race
}

// packed u8 counts -> dinv floats (float4 store per word)
__global__ void k_dinv2(const u32* __restrict__ degp, float* __restrict__ dinv) {
  int w = blockIdx.x * blockDim.x + threadIdx.x;
  if (w < WPG * NGROUPS) {
    u32 c = degp[w];
    float4 o;
    o.x = 1.0f / sqrtf((float)(c & 0xFFu) + 1e-12f);
    o.y = 1.0f / sqrtf((float)((c >> 8) & 0xFFu) + 1e-12f);
    o.z = 1.0f / sqrtf((float)((c >> 16) & 0xFFu) + 1e-12f);
    o.w = 1.0f / sqrtf((float)((c >> 24) & 0xFFu) + 1e-12f);
    *reinterpret_cast<float4*>(dinv + w * 4) = o;
  }
}

__global__ void k_final(const int* __restrict__ rows, const int* __restrict__ cols,
                        const float* __restrict__ vals, const u32* __restrict__ mbits,
                        const float* __restrict__ dinv, const u32* __restrict__ scalars,
                        float* __restrict__ out) {
  u32 anyAlive = scalars[7];
  int stride = gridDim.x * blockDim.x * 4;
  for (int e0 = (blockIdx.x * blockDim.x + threadIdx.x) * 4; e0 < N_EDGES; e0 += stride) {
    u32 q = (mbits[e0 >> 5] >> (e0 & 31)) & 0xFu;
    int4 r4 = *reinterpret_cast<const int4*>(rows + e0);
    int4 c4 = *reinterpret_cast<const int4*>(cols + e0);
    const int rr[4] = {r4.x, r4.y, r4.z, r4.w};
    const int cc[4] = {c4.x, c4.y, c4.z, c4.w};
    float4 enc, msk;
    float ev[4], mv[4];
#pragma unroll
    for (int j = 0; j < 4; j++) {
      u32 mb = (q >> j) & 1u;
      float nv = 0.0f;
      if (!mb) nv = dinv[rr[j]] * dinv[cc[j]];
      ev[j] = nv;
      mv[j] = mb ? 1.0f : 0.0f;
    }
    if (!anyAlive) {
      float4 v4 = *reinterpret_cast<const float4*>(vals + e0);
      ev[0] = v4.x; ev[1] = v4.y; ev[2] = v4.z; ev[3] = v4.w;
    }
    enc.x = ev[0]; enc.y = ev[1]; enc.z = ev[2]; enc.w = ev[3];
    msk.x = mv[0]; msk.y = mv[1]; msk.z = mv[2]; msk.w = mv[3];
    *reinterpret_cast<float4*>(out + e0)            = enc;
    *reinterpret_cast<float4*>(out + N_EDGES + e0)  = msk;
  }
}

extern "C" void kernel_launch(void* const* d_in, const int* in_sizes, int n_in,
                              void* d_out, int out_size, void* d_ws, size_t ws_size,
                              hipStream_t stream) {
  const int*   rows  = (const int*)d_in[0];
  const int*   cols  = (const int*)d_in[1];
  const float* vals  = (const float*)d_in[2];
  const int*   seeds = (const int*)d_in[3];
  int n_seeds = in_sizes[3];
  float* out = (float*)d_out;

  if (ws_size < WS_NEED) return;

  char* ws = (char*)d_ws;
  u32*   mbits  = (u32*)(ws + OFF_MBITS);
  u32*   seedb  = (u32*)(ws + OFF_SEEDB);
  u32*   candb  = (u32*)(ws + OFF_CANDB);
  u32*   mvals  = (u32*)(ws + OFF_MVALS);
  u32*   degp   = (u32*)(ws + OFF_DEG);
  float* dinv   = (float*)(ws + OFF_MVALS);   // mvals retired after the mask loop
  u32*   hist1  = (u32*)(ws + OFF_HIST1);
  u32*   hist2  = (u32*)(ws + OFF_HIST2);
  u32*   tiebuf = (u32*)(ws + OFF_TIEBUF);
  u32*   scal   = (u32*)(ws + OFF_SCAL);

  // ----- host-side key derivation: key = jax.random.key(42) = (0, 42); two splits -----
  u32 sub[2][2];
  u32 ka = 0u, kb = 42u;
  for (int i = 0; i < 2; i++) {
#if TF_PARTITIONABLE
    u32 nk0, nk1, sa, sb_;
    tf2x32(ka, kb, 0u, 0u, nk0, nk1);
    tf2x32(ka, kb, 0u, 1u, sa, sb_);
    sub[i][0] = sa; sub[i][1] = sb_;
    ka = nk0; kb = nk1;
#else
    u32 a0, a1, b0, b1;
    tf2x32(ka, kb, 0u, 2u, a0, a1);
    tf2x32(ka, kb, 1u, 3u, b0, b1);
    sub[i][0] = a1; sub[i][1] = b1;
    ka = a0; kb = b0;
#endif
  }

  hipMemsetAsync(ws, 0, WS_NEED, stream);
  k_scatter_seeds<<<(n_seeds + BLK - 1) / BLK, BLK, 0, stream>>>(seeds, n_seeds, seedb);

  for (int i = 0; i < MASK_DEPTH; i++) {
    if (i > 0) {
      hipMemsetAsync(candb, 0, SEED_WORDS * sizeof(u32), stream);
      hipMemsetAsync(ws + OFF_HIST1, 0, WS_NEED - OFF_HIST1, stream);
    }
    int do_cand = (i != MASK_DEPTH - 1);
    if (do_cand) {
      k_mark2<1><<<MARK_GRID_CAND, MARK_BLK, 0, stream>>>(rows, cols, mbits, seedb, candb);
    } else {
      k_mark2<0><<<MARK_GRID_LAST, MARK_BLK, 0, stream>>>(rows, cols, mbits, seedb, candb);
      break;
    }
    k_count_cand<<<64, BLK, 0, stream>>>(candb, scal);
    k_mvals_hist1<<<NODE_GRID, BLK, 0, stream>>>(sub[i][0], sub[i][1], candb, mvals, hist1);
    k_find_bucket<4096><<<1, BLK, 0, stream>>>(hist1, scal, 0, i + 1);
    k_hist2<<<NODE_GRID, BLK, 0, stream>>>(candb, mvals, scal, hist2);
    k_find_bucket<2048><<<1, BLK, 0, stream>>>(hist2, scal, 1, 0);
    hipMemsetAsync(seedb, 0, SEED_WORDS * sizeof(u32), stream);   // full-replacement semantics
    k_select<<<NODE_GRID, BLK, 0, stream>>>(candb, mvals, scal, seedb, tiebuf);
    k_ties<<<1, BLK, 0, stream>>>(scal, tiebuf, seedb);
  }

  k_deg_lds<<<DEG_GRID, DEG_BLK, 0, stream>>>(rows, mbits, degp, scal);
  k_dinv2<<<(WPG * NGROUPS + BLK - 1) / BLK, BLK, 0, stream>>>(degp, dinv);
  k_final<<<EDGE_GRID, BLK, 0, stream>>>(rows, cols, vals, mbits, dinv, scal, out);
}

// Round 7
// 616.135 us; speedup vs baseline: 2.5159x; 1.3771x over previous
//
#include <hip/hip_runtime.h>
#include <stdint.h>

typedef unsigned int u32;
typedef unsigned char u8;

#define N_NODES 500000
#define N_EDGES 16000000
#define NWORDS_E 500000            // N_EDGES / 32
#define MASK_DEPTH 3
#define BLK 256
#define EDGE_GRID 2048
#define NODE_GRID 1024
#define TIE_CAP 8192
#define SEED_WORDS 15625           // ceil(500000/32)

// k_mark3: wave-cooperative marking, ballot-assembled mask words
#define MARK_BLK 1024
#define MARK_GRID_CAND 256         // 1 block/CU (125KB LDS)
#define MARK_GRID_LAST 512         // 2 blocks/CU (62.5KB LDS)

// degree-count privatization
#define DEG_BLK 512
#define DEG_GRID 512               // 8 groups x 64 blocks; 2 blocks/CU
#define NGROUPS 8
#define NPG 62500                  // nodes per group (500000/8)
#define WPG 15625                  // u32 words per group (4 packed u8 each)

#define TF_PARTITIONABLE 1

// ---------------- workspace layout (bytes) ----------------
#define OFF_MBITS   0u             // u32[NWORDS_E]     = 2,000,000 B
#define OFF_SEEDB   2000000u       // u32[SEED_WORDS]   =    62,500 B (+pad)
#define OFF_CANDB   2062528u       // u32[SEED_WORDS]   =    62,500 B (+pad)
#define OFF_MVALS   2125056u       // u32[N_NODES]      = 2,000,000 B (reused as dinv after loop)
#define OFF_DEG     4125056u       // u32[WPG*NGROUPS]  =   500,000 B packed u8 degree counts
#define OFF_HIST1   4625056u       // u32[4096]
#define OFF_HIST2   4641440u       // u32[2048]
#define OFF_TIEBUF  4649632u       // u32[TIE_CAP]
#define OFF_SCAL    4682400u       // u32[64]
#define WS_NEED     4682656u
// scalars: [0]=n_cand [1]=keep_num [2]=b* [3]=rem1 [4]=m* [5]=rem2 [6]=tie_count [7]=any_alive [8]=valid

// Threefry-2x32, 20 rounds (exactly JAX's threefry2x32_p)
__host__ __device__ inline void tf2x32(u32 k0, u32 k1, u32 x0, u32 x1, u32& o0, u32& o1) {
  u32 ks0 = k0, ks1 = k1, ks2 = k0 ^ k1 ^ 0x1BD11BDAu;
  x0 += ks0; x1 += ks1;
#define TFR(r) { x0 += x1; x1 = (x1 << (r)) | (x1 >> (32 - (r))); x1 ^= x0; }
  TFR(13) TFR(15) TFR(26) TFR(6)   x0 += ks1; x1 += ks2 + 1u;
  TFR(17) TFR(29) TFR(16) TFR(24)  x0 += ks2; x1 += ks0 + 2u;
  TFR(13) TFR(15) TFR(26) TFR(6)   x0 += ks0; x1 += ks1 + 3u;
  TFR(17) TFR(29) TFR(16) TFR(24)  x0 += ks1; x1 += ks2 + 4u;
  TFR(13) TFR(15) TFR(26) TFR(6)   x0 += ks2; x1 += ks0 + 5u;
#undef TFR
  o0 = x0; o1 = x1;
}

// deposit 8 bits at every 4th position (bit k -> bit 4k)
__device__ inline u32 spread4(u32 x) {
  x &= 0xFFu;
  x = (x | (x << 12)) & 0x000F000Fu;
  x = (x | (x << 6))  & 0x03030303u;
  x = (x | (x << 3))  & 0x11111111u;
  return x;
}

__global__ void k_scatter_seeds(const int* __restrict__ seeds, int ns, u32* __restrict__ seedbits) {
  int i = blockIdx.x * blockDim.x + threadIdx.x;
  if (i < ns) {
    int v = seeds[i];
    atomicOr(&seedbits[v >> 5], 1u << (v & 31));
  }
}

// Wave-cooperative marking: each wave owns 256 consecutive edges (= 8 mbits words).
// Lane i loads int4 rows/cols at e0+4i (lane-contiguous, 1KB/instr). Hit bits are
// ballot-assembled into mask words by lanes 0..7 (wave-owned words -> plain store).
// Seed bitset in LDS; cand bitset privatized in LDS, coalesced atomicOr flush.
template <int DO_CAND>
__global__ __launch_bounds__(MARK_BLK) void
k_mark3(const int* __restrict__ rows, const int* __restrict__ cols,
        u32* __restrict__ mbits, const u32* __restrict__ seedbits,
        u32* __restrict__ candb) {
  __shared__ u32 sb[SEED_WORDS];
  __shared__ u32 cb[DO_CAND ? SEED_WORDS : 4];
  for (int w = threadIdx.x; w < SEED_WORDS; w += MARK_BLK) {
    sb[w] = seedbits[w];
    if (DO_CAND) cb[w] = 0;
  }
  __syncthreads();
  const int lane = threadIdx.x & 63;
  const int nwaves = gridDim.x * (MARK_BLK / 64);
  const int gwave = blockIdx.x * (MARK_BLK / 64) + (threadIdx.x >> 6);
  const int NTILES = NWORDS_E / 8;          // 62500 tiles of 8 words / 256 edges
  for (int tile = gwave; tile < NTILES; tile += nwaves) {
    const int w0 = tile * 8;
    const int e0 = w0 * 32;
    u32 mw = mbits[w0 + (lane >> 3)];       // 8 lanes share one word (1 line / wave)
    u32 q  = (mw >> ((lane & 7) * 4)) & 0xFu;  // this lane's 4 edges' mask bits
    u32 hit = 0;
    if (q != 0xFu) {
      const int eb = e0 + lane * 4;
      int4 r4 = *reinterpret_cast<const int4*>(rows + eb);
      int4 c4 = *reinterpret_cast<const int4*>(cols + eb);
      const int rr[4] = {r4.x, r4.y, r4.z, r4.w};
      const int cc[4] = {c4.x, c4.y, c4.z, c4.w};
#pragma unroll
      for (int j = 0; j < 4; j++) {
        if ((q >> j) & 1u) continue;
        int r = rr[j], c = cc[j];
        u32 h = ((sb[r >> 5] >> (r & 31)) | (sb[c >> 5] >> (c & 31))) & 1u;
        if (h) {
          hit |= 1u << j;
          if (DO_CAND) {
            atomicOr(&cb[r >> 5], 1u << (r & 31));
            atomicOr(&cb[c >> 5], 1u << (c & 31));
          }
        }
      }
    }
    // ballot bit i = hit of edge e0 + 4*i + j
    unsigned long long b0 = __ballot(hit & 1u);
    unsigned long long b1 = __ballot(hit & 2u);
    unsigned long long b2 = __ballot(hit & 4u);
    unsigned long long b3 = __ballot(hit & 8u);
    // wave-uniform shfl BEFORE divergent store: lane w needs old word w (held by lane 8w)
    u32 oldw = __shfl(mw, (lane & 7) * 8, 64);
    if (lane < 8) {
      u32 B0 = (u32)(b0 >> (lane * 8)) & 0xFFu;
      u32 B1 = (u32)(b1 >> (lane * 8)) & 0xFFu;
      u32 B2 = (u32)(b2 >> (lane * 8)) & 0xFFu;
      u32 B3 = (u32)(b3 >> (lane * 8)) & 0xFFu;
      u32 word = spread4(B0) | (spread4(B1) << 1) | (spread4(B2) << 2) | (spread4(B3) << 3);
      if (word) mbits[w0 + lane] = oldw | word;   // wave-owned word: plain store
    }
  }
  if (DO_CAND) {
    __syncthreads();
    for (int w = threadIdx.x; w < SEED_WORDS; w += MARK_BLK) {
      u32 c = cb[w];
      if (c) atomicOr(&candb[w], c);
    }
  }
}

__global__ void k_count_cand(const u32* __restrict__ candb, u32* __restrict__ scalars) {
  __shared__ u32 red[BLK];
  u32 s = 0;
  int stride = gridDim.x * blockDim.x;
  for (int w = blockIdx.x * blockDim.x + threadIdx.x; w < SEED_WORDS; w += stride)
    s += (u32)__popc(candb[w]);
  red[threadIdx.x] = s; __syncthreads();
  for (int o = BLK / 2; o > 0; o >>= 1) {
    if (threadIdx.x < (u32)o) red[threadIdx.x] += red[threadIdx.x + o];
    __syncthreads();
  }
  if (threadIdx.x == 0) atomicAdd(&scalars[0], red[0]);
}

// Per-node uniform bits (top 23 bits rank-determining) + coarse histogram over candidates.
__global__ void k_mvals_hist1(u32 s0, u32 s1, const u32* __restrict__ candb,
                              u32* __restrict__ mvals, u32* __restrict__ hist1) {
#if TF_PARTITIONABLE
  int stride = gridDim.x * blockDim.x;
  for (int v = blockIdx.x * blockDim.x + threadIdx.x; v < N_NODES; v += stride) {
    u32 a, b; tf2x32(s0, s1, 0u, (u32)v, a, b);
    u32 m = (a ^ b) >> 9;
    mvals[v] = m;
    if ((candb[v >> 5] >> (v & 31)) & 1u) atomicAdd(&hist1[m >> 11], 1u);
  }
#else
  const int H = N_NODES / 2;
  int stride = gridDim.x * blockDim.x;
  for (int j = blockIdx.x * blockDim.x + threadIdx.x; j < H; j += stride) {
    u32 a, b; tf2x32(s0, s1, (u32)j, (u32)(j + H), a, b);
    u32 m0 = a >> 9, m1 = b >> 9;
    mvals[j] = m0; mvals[j + H] = m1;
    if ((candb[j >> 5] >> (j & 31)) & 1u)                 atomicAdd(&hist1[m0 >> 11], 1u);
    if ((candb[(j + H) >> 5] >> ((j + H) & 31)) & 1u)     atomicAdd(&hist1[m1 >> 11], 1u);
  }
#endif
}

// Single block: find bucket containing the K-th smallest; write bucket + remainder.
template <int NB>
__global__ void k_find_bucket(const u32* __restrict__ hist, u32* __restrict__ scalars,
                              int stage, int shift) {
  __shared__ u32 warpsum[BLK / 64];
  int tid = threadIdx.x;
  u32 K, valid;
  if (stage == 0) {
    u32 nc = scalars[0];
    K = nc >> shift;                       // == floor(n_cand * 0.5^(i+1)) exactly
    valid = (K > 0) ? 1u : 0u;
    if (tid == 0) { scalars[1] = K; scalars[8] = valid; }
  } else {
    valid = scalars[8];
    K = scalars[3];
  }
  if (!valid) return;
  constexpr int CH = NB / BLK;
  u32 loc[CH];
  u32 s = 0;
  int base = tid * CH;
#pragma unroll
  for (int i = 0; i < CH; i++) { loc[i] = hist[base + i]; s += loc[i]; }
  u32 x = s;
  for (int off = 1; off < 64; off <<= 1) {
    u32 y = __shfl_up(x, off, 64);
    if ((tid & 63) >= off) x += y;
  }
  if ((tid & 63) == 63) warpsum[tid >> 6] = x;
  __syncthreads();
  u32 woff = 0;
  for (int w = 0; w < (tid >> 6); w++) woff += warpsum[w];
  u32 run = woff + x - s;
#pragma unroll
  for (int i = 0; i < CH; i++) {
    u32 h = loc[i];
    if (h && K > run && K <= run + h) {
      if (stage == 0) { scalars[2] = (u32)(base + i); scalars[3] = K - run; }
      else            { scalars[4] = (scalars[2] << 11) | (u32)(base + i); scalars[5] = K - run; }
    }
    run += h;
  }
}

__global__ void k_hist2(const u32* __restrict__ candb, const u32* __restrict__ mvals,
                        const u32* __restrict__ scalars, u32* __restrict__ hist2) {
  if (!scalars[8]) return;
  u32 bstar = scalars[2];
  int stride = gridDim.x * blockDim.x;
  for (int v = blockIdx.x * blockDim.x + threadIdx.x; v < N_NODES; v += stride) {
    if ((candb[v >> 5] >> (v & 31)) & 1u) {
      u32 m = mvals[v];
      if ((m >> 11) == bstar) atomicAdd(&hist2[m & 2047u], 1u);
    }
  }
}

// seedbits must be zeroed before this (full-replacement semantics).
__global__ void k_select(const u32* __restrict__ candb, const u32* __restrict__ mvals,
                         u32* __restrict__ scalars, u32* __restrict__ seedbits,
                         u32* __restrict__ tiebuf) {
  if (!scalars[8]) return;
  u32 mstar = scalars[4];
  int stride = gridDim.x * blockDim.x;
  for (int v = blockIdx.x * blockDim.x + threadIdx.x; v < N_NODES; v += stride) {
    if ((candb[v >> 5] >> (v & 31)) & 1u) {
      u32 m = mvals[v];
      if (m < mstar) atomicOr(&seedbits[v >> 5], 1u << (v & 31));
      else if (m == mstar) {
        u32 p = atomicAdd(&scalars[6], 1u);
        if (p < TIE_CAP) tiebuf[p] = (u32)v;
      }
    }
  }
}

// Stable tie-break: among nodes with m == m*, keep the rem2 smallest node indices.
__global__ void k_ties(u32* __restrict__ scalars, const u32* __restrict__ tiebuf,
                       u32* __restrict__ seedbits) {
  if (!scalars[8]) return;
  u32 T = scalars[6]; if (T > TIE_CAP) T = TIE_CAP;
  u32 rem2 = scalars[5];
  for (u32 i = threadIdx.x; i < T; i += blockDim.x) {
    u32 v = tiebuf[i];
    u32 rank = 0;
    for (u32 j = 0; j < T; j++) rank += (tiebuf[j] < v) ? 1u : 0u;
    if (rank < rem2) atomicOr(&seedbits[v >> 5], 1u << (v & 31));
  }
}

// Privatized degree count: 8 node-groups; each block owns one group's 62.5K nodes
// as packed-u8 LDS counters (max row degree ~75 << 255, cross-block field sums too).
__global__ __launch_bounds__(DEG_BLK) void
k_deg_lds(const int* __restrict__ rows, const u32* __restrict__ mbits,
          u32* __restrict__ degp, u32* __restrict__ scalars) {
  __shared__ u32 lcnt[WPG];
  int group = blockIdx.x & (NGROUPS - 1);
  int bsub  = blockIdx.x >> 3;               // 64 blocks per group
  int lo = group * NPG;
  for (int w = threadIdx.x; w < WPG; w += DEG_BLK) lcnt[w] = 0;
  __syncthreads();
  int any = 0;
  const int stride = (DEG_GRID / NGROUPS) * DEG_BLK * 4;
  for (int e0 = (bsub * DEG_BLK + threadIdx.x) * 4; e0 < N_EDGES; e0 += stride) {
    u32 q = (mbits[e0 >> 5] >> (e0 & 31)) & 0xFu;
    if (q == 0xFu) continue;
    int4 r4 = *reinterpret_cast<const int4*>(rows + e0);
    const int rr[4] = {r4.x, r4.y, r4.z, r4.w};
#pragma unroll
    for (int j = 0; j < 4; j++) {
      if (!((q >> j) & 1u)) {
        any = 1;
        u32 r = (u32)(rr[j] - lo);
        if (r < (u32)NPG) atomicAdd(&lcnt[r >> 2], 1u << ((r & 3u) * 8u));
      }
    }
  }
  __syncthreads();
  for (int w = threadIdx.x; w < WPG; w += DEG_BLK) {
    u32 c = lcnt[w];
    if (c) atomicAdd(&degp[group * WPG + w], c);
  }
  if (any) scalars[7] = 1u;   // benign same-value race
}

// packed u8 counts -> dinv floats (float4 store per word)
__global__ void k_dinv2(const u32* __restrict__ degp, float* __restrict__ dinv) {
  int w = blockIdx.x * blockDim.x + threadIdx.x;
  if (w < WPG * NGROUPS) {
    u32 c = degp[w];
    float4 o;
    o.x = 1.0f / sqrtf((float)(c & 0xFFu) + 1e-12f);
    o.y = 1.0f / sqrtf((float)((c >> 8) & 0xFFu) + 1e-12f);
    o.z = 1.0f / sqrtf((float)((c >> 16) & 0xFFu) + 1e-12f);
    o.w = 1.0f / sqrtf((float)((c >> 24) & 0xFFu) + 1e-12f);
    *reinterpret_cast<float4*>(dinv + w * 4) = o;
  }
}

__global__ void k_final(const int* __restrict__ rows, const int* __restrict__ cols,
                        const float* __restrict__ vals, const u32* __restrict__ mbits,
                        const float* __restrict__ dinv, const u32* __restrict__ scalars,
                        float* __restrict__ out) {
  u32 anyAlive = scalars[7];
  int stride = gridDim.x * blockDim.x * 4;
  for (int e0 = (blockIdx.x * blockDim.x + threadIdx.x) * 4; e0 < N_EDGES; e0 += stride) {
    u32 q = (mbits[e0 >> 5] >> (e0 & 31)) & 0xFu;
    int4 r4 = *reinterpret_cast<const int4*>(rows + e0);
    int4 c4 = *reinterpret_cast<const int4*>(cols + e0);
    const int rr[4] = {r4.x, r4.y, r4.z, r4.w};
    const int cc[4] = {c4.x, c4.y, c4.z, c4.w};
    float4 enc, msk;
    float ev[4], mv[4];
#pragma unroll
    for (int j = 0; j < 4; j++) {
      u32 mb = (q >> j) & 1u;
      float nv = 0.0f;
      if (!mb) nv = dinv[rr[j]] * dinv[cc[j]];
      ev[j] = nv;
      mv[j] = mb ? 1.0f : 0.0f;
    }
    if (!anyAlive) {
      float4 v4 = *reinterpret_cast<const float4*>(vals + e0);
      ev[0] = v4.x; ev[1] = v4.y; ev[2] = v4.z; ev[3] = v4.w;
    }
    enc.x = ev[0]; enc.y = ev[1]; enc.z = ev[2]; enc.w = ev[3];
    msk.x = mv[0]; msk.y = mv[1]; msk.z = mv[2]; msk.w = mv[3];
    *reinterpret_cast<float4*>(out + e0)            = enc;
    *reinterpret_cast<float4*>(out + N_EDGES + e0)  = msk;
  }
}

extern "C" void kernel_launch(void* const* d_in, const int* in_sizes, int n_in,
                              void* d_out, int out_size, void* d_ws, size_t ws_size,
                              hipStream_t stream) {
  const int*   rows  = (const int*)d_in[0];
  const int*   cols  = (const int*)d_in[1];
  const float* vals  = (const float*)d_in[2];
  const int*   seeds = (const int*)d_in[3];
  int n_seeds = in_sizes[3];
  float* out = (float*)d_out;

  if (ws_size < WS_NEED) return;

  char* ws = (char*)d_ws;
  u32*   mbits  = (u32*)(ws + OFF_MBITS);
  u32*   seedb  = (u32*)(ws + OFF_SEEDB);
  u32*   candb  = (u32*)(ws + OFF_CANDB);
  u32*   mvals  = (u32*)(ws + OFF_MVALS);
  u32*   degp   = (u32*)(ws + OFF_DEG);
  float* dinv   = (float*)(ws + OFF_MVALS);   // mvals retired after the mask loop
  u32*   hist1  = (u32*)(ws + OFF_HIST1);
  u32*   hist2  = (u32*)(ws + OFF_HIST2);
  u32*   tiebuf = (u32*)(ws + OFF_TIEBUF);
  u32*   scal   = (u32*)(ws + OFF_SCAL);

  // ----- host-side key derivation: key = jax.random.key(42) = (0, 42); two splits -----
  u32 sub[2][2];
  u32 ka = 0u, kb = 42u;
  for (int i = 0; i < 2; i++) {
#if TF_PARTITIONABLE
    u32 nk0, nk1, sa, sb_;
    tf2x32(ka, kb, 0u, 0u, nk0, nk1);
    tf2x32(ka, kb, 0u, 1u, sa, sb_);
    sub[i][0] = sa; sub[i][1] = sb_;
    ka = nk0; kb = nk1;
#else
    u32 a0, a1, b0, b1;
    tf2x32(ka, kb, 0u, 2u, a0, a1);
    tf2x32(ka, kb, 1u, 3u, b0, b1);
    sub[i][0] = a1; sub[i][1] = b1;
    ka = a0; kb = b0;
#endif
  }

  hipMemsetAsync(ws, 0, WS_NEED, stream);
  k_scatter_seeds<<<(n_seeds + BLK - 1) / BLK, BLK, 0, stream>>>(seeds, n_seeds, seedb);

  for (int i = 0; i < MASK_DEPTH; i++) {
    if (i > 0) {
      hipMemsetAsync(candb, 0, SEED_WORDS * sizeof(u32), stream);
      hipMemsetAsync(ws + OFF_HIST1, 0, WS_NEED - OFF_HIST1, stream);
    }
    int do_cand = (i != MASK_DEPTH - 1);
    if (do_cand) {
      k_mark3<1><<<MARK_GRID_CAND, MARK_BLK, 0, stream>>>(rows, cols, mbits, seedb, candb);
    } else {
      k_mark3<0><<<MARK_GRID_LAST, MARK_BLK, 0, stream>>>(rows, cols, mbits, seedb, candb);
      break;
    }
    k_count_cand<<<64, BLK, 0, stream>>>(candb, scal);
    k_mvals_hist1<<<NODE_GRID, BLK, 0, stream>>>(sub[i][0], sub[i][1], candb, mvals, hist1);
    k_find_bucket<4096><<<1, BLK, 0, stream>>>(hist1, scal, 0, i + 1);
    k_hist2<<<NODE_GRID, BLK, 0, stream>>>(candb, mvals, scal, hist2);
    k_find_bucket<2048><<<1, BLK, 0, stream>>>(hist2, scal, 1, 0);
    hipMemsetAsync(seedb, 0, SEED_WORDS * sizeof(u32), stream);   // full-replacement semantics
    k_select<<<NODE_GRID, BLK, 0, stream>>>(candb, mvals, scal, seedb, tiebuf);
    k_ties<<<1, BLK, 0, stream>>>(scal, tiebuf, seedb);
  }

  k_deg_lds<<<DEG_GRID, DEG_BLK, 0, stream>>>(rows, mbits, degp, scal);
  k_dinv2<<<(WPG * NGROUPS + BLK - 1) / BLK, BLK, 0, stream>>>(degp, dinv);
  k_final<<<EDGE_GRID, BLK, 0, stream>>>(rows, cols, vals, mbits, dinv, scal, out);
}

// Round 10
// 568.417 us; speedup vs baseline: 2.7271x; 1.0839x over previous
//
#include <hip/hip_runtime.h>
#include <stdint.h>

typedef unsigned int u32;
typedef unsigned char u8;

#define N_NODES 500000
#define N_EDGES 16000000
#define NWORDS_E 500000            // N_EDGES / 32
#define MASK_DEPTH 3
#define BLK 256
#define EDGE_GRID 2048
#define NODE_GRID 1024
#define TIE_CAP 8192
#define SEED_WORDS 15625           // ceil(500000/32)

// k_mark3: wave-cooperative marking, ballot-assembled mask words
#define MARK_BLK 1024
#define MARK_GRID_CAND 256         // 1 block/CU (125KB LDS)
#define MARK_GRID_LAST 512         // 2 blocks/CU (62.5KB LDS)

// degree-count privatization: 4 groups, 125KB LDS counters, 1 block/CU
#define DEG_BLK 1024
#define DEG_NGROUPS 4
#define DEG_BPG 64                 // blocks per group
#define DEG_GRID (DEG_NGROUPS * DEG_BPG)   // 256 blocks
#define DEG_NPG 125000             // nodes per group (500000/4)
#define DEG_WPG 31250              // u32 words per group (4 packed u8 each) = 125KB

#define TF_PARTITIONABLE 1

// ---------------- workspace layout (bytes) ----------------
#define OFF_MBITS   0u             // u32[NWORDS_E]     = 2,000,000 B
#define OFF_SEEDB   2000000u       // u32[SEED_WORDS]   =    62,500 B (+pad)
#define OFF_CANDB   2062528u       // u32[SEED_WORDS]   =    62,500 B (+pad)
#define OFF_MVALS   2125056u       // u32[N_NODES]      = 2,000,000 B (reused as dinv after loop)
#define OFF_DEG     4125056u       // u32[125000]       =   500,000 B packed u8 degree counts
#define OFF_HIST1   4625056u       // u32[4096]
#define OFF_HIST2   4641440u       // u32[2048]
#define OFF_TIEBUF  4649632u       // u32[TIE_CAP]
#define OFF_SCAL    4682400u       // u32[64]
#define WS_NEED     4682656u
// scalars: [0]=n_cand [1]=keep_num [2]=b* [3]=rem1 [4]=m* [5]=rem2 [6]=tie_count [7]=any_alive [8]=valid

// Threefry-2x32, 20 rounds (exactly JAX's threefry2x32_p)
__host__ __device__ inline void tf2x32(u32 k0, u32 k1, u32 x0, u32 x1, u32& o0, u32& o1) {
  u32 ks0 = k0, ks1 = k1, ks2 = k0 ^ k1 ^ 0x1BD11BDAu;
  x0 += ks0; x1 += ks1;
#define TFR(r) { x0 += x1; x1 = (x1 << (r)) | (x1 >> (32 - (r))); x1 ^= x0; }
  TFR(13) TFR(15) TFR(26) TFR(6)   x0 += ks1; x1 += ks2 + 1u;
  TFR(17) TFR(29) TFR(16) TFR(24)  x0 += ks2; x1 += ks0 + 2u;
  TFR(13) TFR(15) TFR(26) TFR(6)   x0 += ks0; x1 += ks1 + 3u;
  TFR(17) TFR(29) TFR(16) TFR(24)  x0 += ks1; x1 += ks2 + 4u;
  TFR(13) TFR(15) TFR(26) TFR(6)   x0 += ks2; x1 += ks0 + 5u;
#undef TFR
  o0 = x0; o1 = x1;
}

// deposit 8 bits at every 4th position (bit k -> bit 4k)
__device__ inline u32 spread4(u32 x) {
  x &= 0xFFu;
  x = (x | (x << 12)) & 0x000F000Fu;
  x = (x | (x << 6))  & 0x03030303u;
  x = (x | (x << 3))  & 0x11111111u;
  return x;
}

__global__ void k_scatter_seeds(const int* __restrict__ seeds, int ns, u32* __restrict__ seedbits) {
  int i = blockIdx.x * blockDim.x + threadIdx.x;
  if (i < ns) {
    int v = seeds[i];
    atomicOr(&seedbits[v >> 5], 1u << (v & 31));
  }
}

// Wave-cooperative marking: each wave owns 256 consecutive edges (= 8 mbits words).
// Lane i loads int4 rows/cols at e0+4i (lane-contiguous, 1KB/instr). Hit bits are
// ballot-assembled into mask words by lanes 0..7 (wave-owned words -> plain store).
// Seed bitset in LDS; cand bitset privatized in LDS, coalesced atomicOr flush.
template <int DO_CAND>
__global__ __launch_bounds__(MARK_BLK) void
k_mark3(const int* __restrict__ rows, const int* __restrict__ cols,
        u32* __restrict__ mbits, const u32* __restrict__ seedbits,
        u32* __restrict__ candb) {
  __shared__ u32 sb[SEED_WORDS];
  __shared__ u32 cb[DO_CAND ? SEED_WORDS : 4];
  for (int w = threadIdx.x; w < SEED_WORDS; w += MARK_BLK) {
    sb[w] = seedbits[w];
    if (DO_CAND) cb[w] = 0;
  }
  __syncthreads();
  const int lane = threadIdx.x & 63;
  const int nwaves = gridDim.x * (MARK_BLK / 64);
  const int gwave = blockIdx.x * (MARK_BLK / 64) + (threadIdx.x >> 6);
  const int NTILES = NWORDS_E / 8;          // 62500 tiles of 8 words / 256 edges
  for (int tile = gwave; tile < NTILES; tile += nwaves) {
    const int w0 = tile * 8;
    const int e0 = w0 * 32;
    u32 mw = mbits[w0 + (lane >> 3)];       // 8 lanes share one word (1 line / wave)
    u32 q  = (mw >> ((lane & 7) * 4)) & 0xFu;  // this lane's 4 edges' mask bits
    u32 hit = 0;
    if (q != 0xFu) {
      const int eb = e0 + lane * 4;
      int4 r4 = *reinterpret_cast<const int4*>(rows + eb);
      int4 c4 = *reinterpret_cast<const int4*>(cols + eb);
      const int rr[4] = {r4.x, r4.y, r4.z, r4.w};
      const int cc[4] = {c4.x, c4.y, c4.z, c4.w};
#pragma unroll
      for (int j = 0; j < 4; j++) {
        if ((q >> j) & 1u) continue;
        int r = rr[j], c = cc[j];
        u32 h = ((sb[r >> 5] >> (r & 31)) | (sb[c >> 5] >> (c & 31))) & 1u;
        if (h) {
          hit |= 1u << j;
          if (DO_CAND) {
            atomicOr(&cb[r >> 5], 1u << (r & 31));
            atomicOr(&cb[c >> 5], 1u << (c & 31));
          }
        }
      }
    }
    // ballot bit i = hit of edge e0 + 4*i + j
    unsigned long long b0 = __ballot(hit & 1u);
    unsigned long long b1 = __ballot(hit & 2u);
    unsigned long long b2 = __ballot(hit & 4u);
    unsigned long long b3 = __ballot(hit & 8u);
    // wave-uniform shfl BEFORE divergent store: lane w needs old word w (held by lane 8w)
    u32 oldw = __shfl(mw, (lane & 7) * 8, 64);
    if (lane < 8) {
      u32 B0 = (u32)(b0 >> (lane * 8)) & 0xFFu;
      u32 B1 = (u32)(b1 >> (lane * 8)) & 0xFFu;
      u32 B2 = (u32)(b2 >> (lane * 8)) & 0xFFu;
      u32 B3 = (u32)(b3 >> (lane * 8)) & 0xFFu;
      u32 word = spread4(B0) | (spread4(B1) << 1) | (spread4(B2) << 2) | (spread4(B3) << 3);
      if (word) mbits[w0 + lane] = oldw | word;   // wave-owned word: plain store
    }
  }
  if (DO_CAND) {
    __syncthreads();
    for (int w = threadIdx.x; w < SEED_WORDS; w += MARK_BLK) {
      u32 c = cb[w];
      if (c) atomicOr(&candb[w], c);
    }
  }
}

__global__ void k_count_cand(const u32* __restrict__ candb, u32* __restrict__ scalars) {
  __shared__ u32 red[BLK];
  u32 s = 0;
  int stride = gridDim.x * blockDim.x;
  for (int w = blockIdx.x * blockDim.x + threadIdx.x; w < SEED_WORDS; w += stride)
    s += (u32)__popc(candb[w]);
  red[threadIdx.x] = s; __syncthreads();
  for (int o = BLK / 2; o > 0; o >>= 1) {
    if (threadIdx.x < (u32)o) red[threadIdx.x] += red[threadIdx.x + o];
    __syncthreads();
  }
  if (threadIdx.x == 0) atomicAdd(&scalars[0], red[0]);
}

// Per-node uniform bits (top 23 bits rank-determining) + coarse histogram over candidates.
__global__ void k_mvals_hist1(u32 s0, u32 s1, const u32* __restrict__ candb,
                              u32* __restrict__ mvals, u32* __restrict__ hist1) {
#if TF_PARTITIONABLE
  int stride = gridDim.x * blockDim.x;
  for (int v = blockIdx.x * blockDim.x + threadIdx.x; v < N_NODES; v += stride) {
    u32 a, b; tf2x32(s0, s1, 0u, (u32)v, a, b);
    u32 m = (a ^ b) >> 9;
    mvals[v] = m;
    if ((candb[v >> 5] >> (v & 31)) & 1u) atomicAdd(&hist1[m >> 11], 1u);
  }
#else
  const int H = N_NODES / 2;
  int stride = gridDim.x * blockDim.x;
  for (int j = blockIdx.x * blockDim.x + threadIdx.x; j < H; j += stride) {
    u32 a, b; tf2x32(s0, s1, (u32)j, (u32)(j + H), a, b);
    u32 m0 = a >> 9, m1 = b >> 9;
    mvals[j] = m0; mvals[j + H] = m1;
    if ((candb[j >> 5] >> (j & 31)) & 1u)                 atomicAdd(&hist1[m0 >> 11], 1u);
    if ((candb[(j + H) >> 5] >> ((j + H) & 31)) & 1u)     atomicAdd(&hist1[m1 >> 11], 1u);
  }
#endif
}

// Single block: find bucket containing the K-th smallest; write bucket + remainder.
template <int NB>
__global__ void k_find_bucket(const u32* __restrict__ hist, u32* __restrict__ scalars,
                              int stage, int shift) {
  __shared__ u32 warpsum[BLK / 64];
  int tid = threadIdx.x;
  u32 K, valid;
  if (stage == 0) {
    u32 nc = scalars[0];
    K = nc >> shift;                       // == floor(n_cand * 0.5^(i+1)) exactly
    valid = (K > 0) ? 1u : 0u;
    if (tid == 0) { scalars[1] = K; scalars[8] = valid; }
  } else {
    valid = scalars[8];
    K = scalars[3];
  }
  if (!valid) return;
  constexpr int CH = NB / BLK;
  u32 loc[CH];
  u32 s = 0;
  int base = tid * CH;
#pragma unroll
  for (int i = 0; i < CH; i++) { loc[i] = hist[base + i]; s += loc[i]; }
  u32 x = s;
  for (int off = 1; off < 64; off <<= 1) {
    u32 y = __shfl_up(x, off, 64);
    if ((tid & 63) >= off) x += y;
  }
  if ((tid & 63) == 63) warpsum[tid >> 6] = x;
  __syncthreads();
  u32 woff = 0;
  for (int w = 0; w < (tid >> 6); w++) woff += warpsum[w];
  u32 run = woff + x - s;
#pragma unroll
  for (int i = 0; i < CH; i++) {
    u32 h = loc[i];
    if (h && K > run && K <= run + h) {
      if (stage == 0) { scalars[2] = (u32)(base + i); scalars[3] = K - run; }
      else            { scalars[4] = (scalars[2] << 11) | (u32)(base + i); scalars[5] = K - run; }
    }
    run += h;
  }
}

__global__ void k_hist2(const u32* __restrict__ candb, const u32* __restrict__ mvals,
                        const u32* __restrict__ scalars, u32* __restrict__ hist2) {
  if (!scalars[8]) return;
  u32 bstar = scalars[2];
  int stride = gridDim.x * blockDim.x;
  for (int v = blockIdx.x * blockDim.x + threadIdx.x; v < N_NODES; v += stride) {
    if ((candb[v >> 5] >> (v & 31)) & 1u) {
      u32 m = mvals[v];
      if ((m >> 11) == bstar) atomicAdd(&hist2[m & 2047u], 1u);
    }
  }
}

// seedbits must be zeroed before this (full-replacement semantics).
__global__ void k_select(const u32* __restrict__ candb, const u32* __restrict__ mvals,
                         u32* __restrict__ scalars, u32* __restrict__ seedbits,
                         u32* __restrict__ tiebuf) {
  if (!scalars[8]) return;
  u32 mstar = scalars[4];
  int stride = gridDim.x * blockDim.x;
  for (int v = blockIdx.x * blockDim.x + threadIdx.x; v < N_NODES; v += stride) {
    if ((candb[v >> 5] >> (v & 31)) & 1u) {
      u32 m = mvals[v];
      if (m < mstar) atomicOr(&seedbits[v >> 5], 1u << (v & 31));
      else if (m == mstar) {
        u32 p = atomicAdd(&scalars[6], 1u);
        if (p < TIE_CAP) tiebuf[p] = (u32)v;
      }
    }
  }
}

// Stable tie-break: among nodes with m == m*, keep the rem2 smallest node indices.
__global__ void k_ties(u32* __restrict__ scalars, const u32* __restrict__ tiebuf,
                       u32* __restrict__ seedbits) {
  if (!scalars[8]) return;
  u32 T = scalars[6]; if (T > TIE_CAP) T = TIE_CAP;
  u32 rem2 = scalars[5];
  for (u32 i = threadIdx.x; i < T; i += blockDim.x) {
    u32 v = tiebuf[i];
    u32 rank = 0;
    for (u32 j = 0; j < T; j++) rank += (tiebuf[j] < v) ? 1u : 0u;
    if (rank < rem2) atomicOr(&seedbits[v >> 5], 1u << (v & 31));
  }
}

// Privatized degree count: 4 node-groups; each block owns one group's 125K nodes
// as packed-u8 LDS counters (125KB LDS, 1 block/CU). Total edge-visits = 4*E
// (half of the previous 8-group scheme); per-CU critical path also halves.
__global__ __launch_bounds__(DEG_BLK) void
k_deg_lds(const int* __restrict__ rows, const u32* __restrict__ mbits,
          u32* __restrict__ degp, u32* __restrict__ scalars) {
  __shared__ u32 lcnt[DEG_WPG];
  int group = blockIdx.x & (DEG_NGROUPS - 1);
  int bsub  = blockIdx.x >> 2;               // 64 blocks per group
  int lo = group * DEG_NPG;
  for (int w = threadIdx.x; w < DEG_WPG; w += DEG_BLK) lcnt[w] = 0;
  __syncthreads();
  int any = 0;
  const int stride = DEG_BPG * DEG_BLK * 4;
  for (int e0 = (bsub * DEG_BLK + threadIdx.x) * 4; e0 < N_EDGES; e0 += stride) {
    u32 q = (mbits[e0 >> 5] >> (e0 & 31)) & 0xFu;
    if (q == 0xFu) continue;
    int4 r4 = *reinterpret_cast<const int4*>(rows + e0);
    const int rr[4] = {r4.x, r4.y, r4.z, r4.w};
#pragma unroll
    for (int j = 0; j < 4; j++) {
      if (!((q >> j) & 1u)) {
        any = 1;
        u32 r = (u32)(rr[j] - lo);
        if (r < (u32)DEG_NPG) atomicAdd(&lcnt[r >> 2], 1u << ((r & 3u) * 8u));
      }
    }
  }
  __syncthreads();
  for (int w = threadIdx.x; w < DEG_WPG; w += DEG_BLK) {
    u32 c = lcnt[w];
    if (c) atomicAdd(&degp[group * DEG_WPG + w], c);
  }
  if (any) scalars[7] = 1u;   // benign same-value race
}

// packed u8 counts -> dinv floats (float4 store per word)
__global__ void k_dinv2(const u32* __restrict__ degp, float* __restrict__ dinv) {
  int w = blockIdx.x * blockDim.x + threadIdx.x;
  if (w < N_NODES / 4) {
    u32 c = degp[w];
    float4 o;
    o.x = 1.0f / sqrtf((float)(c & 0xFFu) + 1e-12f);
    o.y = 1.0f / sqrtf((float)((c >> 8) & 0xFFu) + 1e-12f);
    o.z = 1.0f / sqrtf((float)((c >> 16) & 0xFFu) + 1e-12f);
    o.w = 1.0f / sqrtf((float)((c >> 24) & 0xFFu) + 1e-12f);
    *reinterpret_cast<float4*>(dinv + w * 4) = o;
  }
}

__global__ void k_final(const int* __restrict__ rows, const int* __restrict__ cols,
                        const float* __restrict__ vals, const u32* __restrict__ mbits,
                        const float* __restrict__ dinv, const u32* __restrict__ scalars,
                        float* __restrict__ out) {
  u32 anyAlive = scalars[7];
  int stride = gridDim.x * blockDim.x * 4;
  for (int e0 = (blockIdx.x * blockDim.x + threadIdx.x) * 4; e0 < N_EDGES; e0 += stride) {
    u32 q = (mbits[e0 >> 5] >> (e0 & 31)) & 0xFu;
    int4 r4 = *reinterpret_cast<const int4*>(rows + e0);
    int4 c4 = *reinterpret_cast<const int4*>(cols + e0);
    const int rr[4] = {r4.x, r4.y, r4.z, r4.w};
    const int cc[4] = {c4.x, c4.y, c4.z, c4.w};
    float4 enc, msk;
    float ev[4], mv[4];
#pragma unroll
    for (int j = 0; j < 4; j++) {
      u32 mb = (q >> j) & 1u;
      float nv = 0.0f;
      if (!mb) nv = dinv[rr[j]] * dinv[cc[j]];
      ev[j] = nv;
      mv[j] = mb ? 1.0f : 0.0f;
    }
    if (!anyAlive) {
      float4 v4 = *reinterpret_cast<const float4*>(vals + e0);
      ev[0] = v4.x; ev[1] = v4.y; ev[2] = v4.z; ev[3] = v4.w;
    }
    enc.x = ev[0]; enc.y = ev[1]; enc.z = ev[2]; enc.w = ev[3];
    msk.x = mv[0]; msk.y = mv[1]; msk.z = mv[2]; msk.w = mv[3];
    *reinterpret_cast<float4*>(out + e0)            = enc;
    *reinterpret_cast<float4*>(out + N_EDGES + e0)  = msk;
  }
}

extern "C" void kernel_launch(void* const* d_in, const int* in_sizes, int n_in,
                              void* d_out, int out_size, void* d_ws, size_t ws_size,
                              hipStream_t stream) {
  const int*   rows  = (const int*)d_in[0];
  const int*   cols  = (const int*)d_in[1];
  const float* vals  = (const float*)d_in[2];
  const int*   seeds = (const int*)d_in[3];
  int n_seeds = in_sizes[3];
  float* out = (float*)d_out;

  if (ws_size < WS_NEED) return;

  char* ws = (char*)d_ws;
  u32*   mbits  = (u32*)(ws + OFF_MBITS);
  u32*   seedb  = (u32*)(ws + OFF_SEEDB);
  u32*   candb  = (u32*)(ws + OFF_CANDB);
  u32*   mvals  = (u32*)(ws + OFF_MVALS);
  u32*   degp   = (u32*)(ws + OFF_DEG);
  float* dinv   = (float*)(ws + OFF_MVALS);   // mvals retired after the mask loop
  u32*   hist1  = (u32*)(ws + OFF_HIST1);
  u32*   hist2  = (u32*)(ws + OFF_HIST2);
  u32*   tiebuf = (u32*)(ws + OFF_TIEBUF);
  u32*   scal   = (u32*)(ws + OFF_SCAL);

  // ----- host-side key derivation: key = jax.random.key(42) = (0, 42); two splits -----
  u32 sub[2][2];
  u32 ka = 0u, kb = 42u;
  for (int i = 0; i < 2; i++) {
#if TF_PARTITIONABLE
    u32 nk0, nk1, sa, sb_;
    tf2x32(ka, kb, 0u, 0u, nk0, nk1);
    tf2x32(ka, kb, 0u, 1u, sa, sb_);
    sub[i][0] = sa; sub[i][1] = sb_;
    ka = nk0; kb = nk1;
#else
    u32 a0, a1, b0, b1;
    tf2x32(ka, kb, 0u, 2u, a0, a1);
    tf2x32(ka, kb, 1u, 3u, b0, b1);
    sub[i][0] = a1; sub[i][1] = b1;
    ka = a0; kb = b0;
#endif
  }

  hipMemsetAsync(ws, 0, WS_NEED, stream);
  k_scatter_seeds<<<(n_seeds + BLK - 1) / BLK, BLK, 0, stream>>>(seeds, n_seeds, seedb);

  for (int i = 0; i < MASK_DEPTH; i++) {
    if (i > 0) {
      hipMemsetAsync(candb, 0, SEED_WORDS * sizeof(u32), stream);
      hipMemsetAsync(ws + OFF_HIST1, 0, WS_NEED - OFF_HIST1, stream);
    }
    int do_cand = (i != MASK_DEPTH - 1);
    if (do_cand) {
      k_mark3<1><<<MARK_GRID_CAND, MARK_BLK, 0, stream>>>(rows, cols, mbits, seedb, candb);
    } else {
      k_mark3<0><<<MARK_GRID_LAST, MARK_BLK, 0, stream>>>(rows, cols, mbits, seedb, candb);
      break;
    }
    k_count_cand<<<64, BLK, 0, stream>>>(candb, scal);
    k_mvals_hist1<<<NODE_GRID, BLK, 0, stream>>>(sub[i][0], sub[i][1], candb, mvals, hist1);
    k_find_bucket<4096><<<1, BLK, 0, stream>>>(hist1, scal, 0, i + 1);
    k_hist2<<<NODE_GRID, BLK, 0, stream>>>(candb, mvals, scal, hist2);
    k_find_bucket<2048><<<1, BLK, 0, stream>>>(hist2, scal, 1, 0);
    hipMemsetAsync(seedb, 0, SEED_WORDS * sizeof(u32), stream);   // full-replacement semantics
    k_select<<<NODE_GRID, BLK, 0, stream>>>(candb, mvals, scal, seedb, tiebuf);
    k_ties<<<1, BLK, 0, stream>>>(scal, tiebuf, seedb);
  }

  k_deg_lds<<<DEG_GRID, DEG_BLK, 0, stream>>>(rows, mbits, degp, scal);
  k_dinv2<<<(N_NODES / 4 + BLK - 1) / BLK, BLK, 0, stream>>>(degp, dinv);
  k_final<<<EDGE_GRID, BLK, 0, stream>>>(rows, cols, vals, mbits, dinv, scal, out);
}